// Round 4
// baseline (382.466 us; speedup 1.0000x reference)
//
#include <hip/hip_runtime.h>
#include <hip/hip_bf16.h>
#include <math.h>

// Problem constants (fixed by the reference)
#define BB 32      // batch
#define SS 2048    // seq len
#define DD 64      // dim_s
#define MM 32      // size_m
#define NSKILL 4096
#define CC 64      // scan chunks
#define LL 32      // chunk length = SS/CC

__device__ __forceinline__ float sigmoidf_(float x) {
    return 1.f / (1.f + __expf(-x));
}
__device__ __forceinline__ float tanhf_(float x) {
    float t = __expf(-2.f * fabsf(x));
    float r = (1.f - t) / (1.f + t);
    return copysignf(r, x);
}

// ---------------------------------------------------------------------------
// Kernel 0: transpose weights so each output column is a contiguous row
// (scalar-load friendly). eWt/aWt: [d][i] (64x64). fWt: [d][i] (64x128).
// ---------------------------------------------------------------------------
__global__ __launch_bounds__(256) void k_prep(
    const float* __restrict__ eW, const float* __restrict__ aW,
    const float* __restrict__ fW,
    float* __restrict__ eWt, float* __restrict__ aWt, float* __restrict__ fWt)
{
    const int t = blockIdx.x * 256 + threadIdx.x;   // grid 32*256 = 8192
    if (t < DD * DD) {
        const int i = t >> 6, d = t & 63;
        eWt[d * DD + i] = eW[i * DD + d];
        aWt[d * DD + i] = aW[i * DD + d];
    }
    {   // fW is [128][64]
        const int i = t >> 6, d = t & 63;   // t covers 128*64 = 8192
        fWt[d * 128 + i] = fW[i * DD + d];
    }
}

// ---------------------------------------------------------------------------
// Kernel 1 (v2): lane = token. All weight operands are wave-uniform (SGPR).
// Per lane: k row in 16 float4 regs -> 32 logits in regs -> in-lane softmax
// -> v row in regs -> e/a via runtime d-loop with scalar weight rows.
// No LDS, no __syncthreads.
// ---------------------------------------------------------------------------
__global__ __launch_bounds__(256) void k_token(
    const int* __restrict__ skill, const int* __restrict__ resp,
    const float* __restrict__ k_emb, const float* __restrict__ v_emb,
    const float* __restrict__ Mk,
    const float* __restrict__ eWt, const float* __restrict__ eb,
    const float* __restrict__ aWt, const float* __restrict__ ab,
    float* __restrict__ w_out, float* __restrict__ e_out, float* __restrict__ a_out)
{
    const int tok = blockIdx.x * 256 + threadIdx.x;   // grid 256 -> 65536 lanes
    const int sk = skill[tok];
    const int xc = sk + NSKILL * resp[tok];

    // k row -> registers (16 x float4, per-lane gather; k_emb is 1 MB, L2-hot)
    float4 kq[16];
    const float4* kp = (const float4*)(k_emb + (size_t)sk * DD);
    #pragma unroll
    for (int q = 0; q < 16; ++q) kq[q] = kp[q];

    // logits[m] = dot(k, Mk[m][:])  -- Mk operand uniform -> scalar
    float lg[MM];
    #pragma unroll
    for (int m = 0; m < MM; ++m) {
        const float* mk = Mk + m * DD;
        float a0 = 0.f, a1 = 0.f, a2 = 0.f, a3 = 0.f;
        #pragma unroll
        for (int q = 0; q < 16; ++q) {
            const float4 kv = kq[q];
            a0 = fmaf(kv.x, mk[4 * q + 0], a0);
            a1 = fmaf(kv.y, mk[4 * q + 1], a1);
            a2 = fmaf(kv.z, mk[4 * q + 2], a2);
            a3 = fmaf(kv.w, mk[4 * q + 3], a3);
        }
        lg[m] = (a0 + a1) + (a2 + a3);
    }

    // in-lane softmax over 32 values
    float mx = lg[0];
    #pragma unroll
    for (int m = 1; m < MM; ++m) mx = fmaxf(mx, lg[m]);
    float sm = 0.f;
    #pragma unroll
    for (int m = 0; m < MM; ++m) { lg[m] = __expf(lg[m] - mx); sm += lg[m]; }
    const float inv = 1.f / sm;

    // store w (8 x float4 per lane)
    float4* wp = (float4*)(w_out + (size_t)tok * MM);
    #pragma unroll
    for (int q = 0; q < 8; ++q) {
        float4 wv;
        wv.x = lg[4 * q + 0] * inv; wv.y = lg[4 * q + 1] * inv;
        wv.z = lg[4 * q + 2] * inv; wv.w = lg[4 * q + 3] * inv;
        wp[q] = wv;
    }

    // v row -> registers
    float4 vq[16];
    const float4* vp = (const float4*)(v_emb + (size_t)xc * DD);
    #pragma unroll
    for (int q = 0; q < 16; ++q) vq[q] = vp[q];

    // e/a: runtime loop over output-dim pairs; weight rows are uniform scalars
    float* eo = e_out + (size_t)tok * DD;
    float* ao = a_out + (size_t)tok * DD;
    for (int d = 0; d < DD; d += 2) {
        const float* ec0 = eWt + d * DD;
        const float* ec1 = ec0 + DD;
        const float* ac0 = aWt + d * DD;
        const float* ac1 = ac0 + DD;
        float e0 = eb[d], e1 = eb[d + 1];
        float a0 = ab[d], a1 = ab[d + 1];
        #pragma unroll
        for (int q = 0; q < 16; ++q) {
            const float4 vv = vq[q];
            e0 = fmaf(vv.x, ec0[4 * q + 0], e0); e0 = fmaf(vv.y, ec0[4 * q + 1], e0);
            e0 = fmaf(vv.z, ec0[4 * q + 2], e0); e0 = fmaf(vv.w, ec0[4 * q + 3], e0);
            e1 = fmaf(vv.x, ec1[4 * q + 0], e1); e1 = fmaf(vv.y, ec1[4 * q + 1], e1);
            e1 = fmaf(vv.z, ec1[4 * q + 2], e1); e1 = fmaf(vv.w, ec1[4 * q + 3], e1);
            a0 = fmaf(vv.x, ac0[4 * q + 0], a0); a0 = fmaf(vv.y, ac0[4 * q + 1], a0);
            a0 = fmaf(vv.z, ac0[4 * q + 2], a0); a0 = fmaf(vv.w, ac0[4 * q + 3], a0);
            a1 = fmaf(vv.x, ac1[4 * q + 0], a1); a1 = fmaf(vv.y, ac1[4 * q + 1], a1);
            a1 = fmaf(vv.z, ac1[4 * q + 2], a1); a1 = fmaf(vv.w, ac1[4 * q + 3], a1);
        }
        float2 ev; ev.x = sigmoidf_(e0); ev.y = sigmoidf_(e1);
        float2 av; av.x = tanhf_(a0);    av.y = tanhf_(a1);
        *(float2*)(eo + d) = ev;
        *(float2*)(ao + d) = av;
    }
}

// ---------------------------------------------------------------------------
// Kernel 2 (scan pass 1): per (b, chunk) compose 32 steps into (Abar, Bbar).
// ---------------------------------------------------------------------------
__global__ __launch_bounds__(64) void k_pass1(
    const float* __restrict__ w, const float* __restrict__ mask,
    const float* __restrict__ e, const float* __restrict__ a,
    float* __restrict__ Abar, float* __restrict__ Bbar)
{
    __shared__ float4 wl[LL * MM / 4];
    const int lane = threadIdx.x;
    const int b = blockIdx.x / CC;
    const int c = blockIdx.x % CC;
    const int t0 = c * LL;

    const float4* wg = (const float4*)(w + (size_t)(b * SS + t0) * MM);
    #pragma unroll
    for (int u = 0; u < 4; ++u) {
        const int q4 = lane + 64 * u;
        const int j = q4 >> 3;
        const float s = (mask[b * SS + t0 + j] == 1.f) ? 1.f : 0.f;
        float4 wq = wg[q4];
        wq.x *= s; wq.y *= s; wq.z *= s; wq.w *= s;
        wl[q4] = wq;
    }
    __syncthreads();

    float Ab[MM], Bb[MM];
    #pragma unroll
    for (int i = 0; i < MM; ++i) { Ab[i] = 1.f; Bb[i] = 0.f; }

    const float* ep = e + (size_t)(b * SS + t0) * DD + lane;
    const float* ap = a + (size_t)(b * SS + t0) * DD + lane;
    for (int j = 0; j < LL; ++j) {
        const float ed = ep[j * DD];
        const float ad = ap[j * DD];
        const float4* wlj = wl + j * 8;
        #pragma unroll
        for (int u = 0; u < 8; ++u) {
            const float4 wq = wlj[u];
            float t1;
            t1 = fmaf(-wq.x, ed, 1.f); Ab[4*u+0] *= t1; Bb[4*u+0] = fmaf(Bb[4*u+0], t1, wq.x * ad);
            t1 = fmaf(-wq.y, ed, 1.f); Ab[4*u+1] *= t1; Bb[4*u+1] = fmaf(Bb[4*u+1], t1, wq.y * ad);
            t1 = fmaf(-wq.z, ed, 1.f); Ab[4*u+2] *= t1; Bb[4*u+2] = fmaf(Bb[4*u+2], t1, wq.z * ad);
            t1 = fmaf(-wq.w, ed, 1.f); Ab[4*u+3] *= t1; Bb[4*u+3] = fmaf(Bb[4*u+3], t1, wq.w * ad);
        }
    }
    float* Ao = Abar + (size_t)blockIdx.x * MM * DD + lane;
    float* Bo = Bbar + (size_t)blockIdx.x * MM * DD + lane;
    #pragma unroll
    for (int i = 0; i < MM; ++i) { Ao[i * DD] = Ab[i]; Bo[i * DD] = Bb[i]; }
}

// ---------------------------------------------------------------------------
// Kernel 3 (scan pass 2): sequential over 64 chunks, parallel over B*M*D.
// Writes chunk-start states IN PLACE into Bbar (read before overwrite).
// ---------------------------------------------------------------------------
__global__ __launch_bounds__(256) void k_pass2(
    const float* __restrict__ Abar, float* __restrict__ Bbar_cst,
    const float* __restrict__ Mv0)
{
    const int idx = blockIdx.x * 256 + threadIdx.x;   // over B*M*D = 65536
    const int b = idx >> 11;
    const int md = idx & 2047;
    float s = Mv0[md];
    for (int c = 0; c < CC; ++c) {
        const int off = ((b * CC + c) << 11) + md;
        const float sa = Abar[off];
        const float sb = Bbar_cst[off];
        Bbar_cst[off] = s;           // cstate[b,c] = state at chunk start
        s = fmaf(s, sa, sb);
    }
}

// ---------------------------------------------------------------------------
// Kernel 4 (scan pass 3): replay each chunk from cstate (=Bbar), emit
// read[b, t+1, d] = sum_m w[b,t+1,m] * Mv_after_t[m,d].
// ---------------------------------------------------------------------------
__global__ __launch_bounds__(64) void k_pass3(
    const float* __restrict__ w, const float* __restrict__ mask,
    const float* __restrict__ e, const float* __restrict__ a,
    const float* __restrict__ cstate, float* __restrict__ readv)
{
    __shared__ float4 wl[LL * MM / 4];
    __shared__ float4 wn[LL * MM / 4];
    const int lane = threadIdx.x;
    const int b = blockIdx.x / CC;
    const int c = blockIdx.x % CC;
    const int t0 = c * LL;
    const bool last = (c == CC - 1);

    const float4* wg  = (const float4*)(w + (size_t)(b * SS + t0) * MM);
    const float4* wg2 = (const float4*)(w + (size_t)(b * SS + t0 + 1) * MM);
    #pragma unroll
    for (int u = 0; u < 4; ++u) {
        const int q4 = lane + 64 * u;
        const int j = q4 >> 3;
        const float s = (mask[b * SS + t0 + j] == 1.f) ? 1.f : 0.f;
        float4 wq = wg[q4];
        wq.x *= s; wq.y *= s; wq.z *= s; wq.w *= s;
        wl[q4] = wq;
        float4 wq2;
        if (last && q4 >= 248) wq2 = make_float4(0.f, 0.f, 0.f, 0.f);
        else                   wq2 = wg2[q4];
        wn[q4] = wq2;
    }
    __syncthreads();

    float Mv[MM];
    const float* cs = cstate + (size_t)blockIdx.x * MM * DD + lane;
    #pragma unroll
    for (int i = 0; i < MM; ++i) Mv[i] = cs[i * DD];

    const float* ep = e + (size_t)(b * SS + t0) * DD + lane;
    const float* ap = a + (size_t)(b * SS + t0) * DD + lane;
    float* ro = readv + (size_t)(b * SS + t0 + 1) * DD + lane;
    for (int j = 0; j < LL; ++j) {
        const float ed = ep[j * DD];
        const float ad = ap[j * DD];
        const float4* wlj = wl + j * 8;
        const float4* wnj = wn + j * 8;
        float r0 = 0.f, r1 = 0.f, r2 = 0.f, r3 = 0.f;
        #pragma unroll
        for (int u = 0; u < 8; ++u) {
            const float4 wq = wlj[u];
            const float4 w2 = wnj[u];
            float t1;
            t1 = fmaf(-wq.x, ed, 1.f); Mv[4*u+0] = fmaf(Mv[4*u+0], t1, wq.x * ad); r0 = fmaf(w2.x, Mv[4*u+0], r0);
            t1 = fmaf(-wq.y, ed, 1.f); Mv[4*u+1] = fmaf(Mv[4*u+1], t1, wq.y * ad); r1 = fmaf(w2.y, Mv[4*u+1], r1);
            t1 = fmaf(-wq.z, ed, 1.f); Mv[4*u+2] = fmaf(Mv[4*u+2], t1, wq.z * ad); r2 = fmaf(w2.z, Mv[4*u+2], r2);
            t1 = fmaf(-wq.w, ed, 1.f); Mv[4*u+3] = fmaf(Mv[4*u+3], t1, wq.w * ad); r3 = fmaf(w2.w, Mv[4*u+3], r3);
        }
        if (!(last && j == LL - 1))
            ro[j * DD] = (r0 + r1) + (r2 + r3);
    }
}

// ---------------------------------------------------------------------------
// Kernel 5 (v2): lane = output index. fW columns (fWt rows) are scalar
// operands; read/k rows in registers. p accumulated on the fly.
// ---------------------------------------------------------------------------
__global__ __launch_bounds__(256) void k_final(
    const float* __restrict__ readv, const int* __restrict__ skill,
    const float* __restrict__ k_emb,
    const float* __restrict__ fWt, const float* __restrict__ fb,
    const float* __restrict__ pW, const float* __restrict__ pb,
    float* __restrict__ out)
{
    const int o = blockIdx.x * 256 + threadIdx.x;   // grid 256 -> 65536 lanes
    const bool valid = o < BB * (SS - 1);
    const int oc = valid ? o : 0;
    const int b = oc / (SS - 1);
    const int s = oc - b * (SS - 1) + 1;            // 1..2047
    const size_t tok = (size_t)b * SS + s;

    float4 rq[16], kq[16];
    const float4* rp = (const float4*)(readv + tok * DD);
    const float4* kp = (const float4*)(k_emb + (size_t)skill[tok] * DD);
    #pragma unroll
    for (int q = 0; q < 16; ++q) { rq[q] = rp[q]; kq[q] = kp[q]; }

    float pacc = 0.f;
    for (int d = 0; d < DD; d += 2) {
        const float* c0 = fWt + d * 128;
        const float* c1 = c0 + 128;
        float f0 = fb[d], f1 = fb[d + 1];
        #pragma unroll
        for (int q = 0; q < 16; ++q) {
            const float4 rv = rq[q];
            f0 = fmaf(rv.x, c0[4 * q + 0], f0); f0 = fmaf(rv.y, c0[4 * q + 1], f0);
            f0 = fmaf(rv.z, c0[4 * q + 2], f0); f0 = fmaf(rv.w, c0[4 * q + 3], f0);
            f1 = fmaf(rv.x, c1[4 * q + 0], f1); f1 = fmaf(rv.y, c1[4 * q + 1], f1);
            f1 = fmaf(rv.z, c1[4 * q + 2], f1); f1 = fmaf(rv.w, c1[4 * q + 3], f1);
        }
        #pragma unroll
        for (int q = 0; q < 16; ++q) {
            const float4 kv = kq[q];
            f0 = fmaf(kv.x, c0[64 + 4 * q + 0], f0); f0 = fmaf(kv.y, c0[64 + 4 * q + 1], f0);
            f0 = fmaf(kv.z, c0[64 + 4 * q + 2], f0); f0 = fmaf(kv.w, c0[64 + 4 * q + 3], f0);
            f1 = fmaf(kv.x, c1[64 + 4 * q + 0], f1); f1 = fmaf(kv.y, c1[64 + 4 * q + 1], f1);
            f1 = fmaf(kv.z, c1[64 + 4 * q + 2], f1); f1 = fmaf(kv.w, c1[64 + 4 * q + 3], f1);
        }
        pacc = fmaf(tanhf_(f0), pW[d], pacc);
        pacc = fmaf(tanhf_(f1), pW[d + 1], pacc);
    }
    if (valid) out[o] = pacc + pb[0];
}

// ---------------------------------------------------------------------------
extern "C" void kernel_launch(void* const* d_in, const int* in_sizes, int n_in,
                              void* d_out, int out_size, void* d_ws, size_t ws_size,
                              hipStream_t stream)
{
    const int*   response = (const int*)d_in[1];
    const int*   skill    = (const int*)d_in[2];
    const float* mask     = (const float*)d_in[3];
    const float* k_emb    = (const float*)d_in[4];
    const float* v_emb    = (const float*)d_in[5];
    const float* Mk       = (const float*)d_in[6];
    const float* Mv0      = (const float*)d_in[7];
    const float* eW       = (const float*)d_in[8];
    const float* ebias    = (const float*)d_in[9];
    const float* aW       = (const float*)d_in[10];
    const float* abias    = (const float*)d_in[11];
    const float* fW       = (const float*)d_in[12];
    const float* fbias    = (const float*)d_in[13];
    const float* pW       = (const float*)d_in[14];
    const float* pbias    = (const float*)d_in[15];
    float* out = (float*)d_out;

    // workspace layout (floats); total 23,085,056 floats = 88.06 MiB
    float* ws    = (float*)d_ws;
    float* w_    = ws;                               // B*S*M   = 2,097,152
    float* e_    = w_    + (size_t)BB * SS * MM;     // B*S*D   = 4,194,304
    float* a_    = e_    + (size_t)BB * SS * DD;
    float* Abar  = a_    + (size_t)BB * SS * DD;     // B*C*M*D = 4,194,304
    float* Bbar  = Abar  + (size_t)BB * CC * MM * DD; // doubles as cstate
    float* readv = Bbar  + (size_t)BB * CC * MM * DD; // B*S*D (row s=0 unused)
    float* eWt   = readv + (size_t)BB * SS * DD;     // 4096
    float* aWt   = eWt   + DD * DD;                  // 4096
    float* fWt   = aWt   + DD * DD;                  // 8192

    k_prep <<<32,   256, 0, stream>>>(eW, aW, fW, eWt, aWt, fWt);
    k_token<<<256,  256, 0, stream>>>(skill, response, k_emb, v_emb, Mk,
                                      eWt, ebias, aWt, abias, w_, e_, a_);
    k_pass1<<<BB * CC, 64, 0, stream>>>(w_, mask, e_, a_, Abar, Bbar);
    k_pass2<<<256,  256, 0, stream>>>(Abar, Bbar, Mv0);
    k_pass3<<<BB * CC, 64, 0, stream>>>(w_, mask, e_, a_, Bbar, readv);
    k_final<<<256,  256, 0, stream>>>(readv, skill, k_emb, fWt, fbias,
                                      pW, pbias, out);
}

// Round 5
// 288.149 us; speedup vs baseline: 1.3273x; 1.3273x over previous
//
#include <hip/hip_runtime.h>
#include <hip/hip_bf16.h>
#include <math.h>

// Problem constants (fixed by the reference)
#define BB 32      // batch
#define SS 2048    // seq len
#define DD 64      // dim_s
#define MM 32      // size_m
#define NSKILL 4096
#define CC 64      // scan chunks
#define LL 32      // chunk length = SS/CC

__device__ __forceinline__ float sigmoidf_(float x) {
    return 1.f / (1.f + __expf(-x));
}
__device__ __forceinline__ float tanhf_(float x) {
    float t = __expf(-2.f * fabsf(x));
    float r = (1.f - t) / (1.f + t);
    return copysignf(r, x);
}

// ---------------------------------------------------------------------------
// Kernel 0: transpose weights so each output column is a contiguous row
// (scalar-load friendly). eWt/aWt: [d][i] (64x64). fWt: [d][i] (64x128).
// ---------------------------------------------------------------------------
__global__ __launch_bounds__(256) void k_prep(
    const float* __restrict__ eW, const float* __restrict__ aW,
    const float* __restrict__ fW,
    float* __restrict__ eWt, float* __restrict__ aWt, float* __restrict__ fWt)
{
    const int t = blockIdx.x * 256 + threadIdx.x;   // grid 32*256 = 8192
    if (t < DD * DD) {
        const int i = t >> 6, d = t & 63;
        eWt[d * DD + i] = eW[i * DD + d];
        aWt[d * DD + i] = aW[i * DD + d];
    }
    {   // fW is [128][64]
        const int i = t >> 6, d = t & 63;   // t covers 128*64 = 8192
        fWt[d * 128 + i] = fW[i * DD + d];
    }
}

// ---------------------------------------------------------------------------
// Kernel 1 (v3): 64-thread role blocks, lane = token.
//   even blocks: w = softmax(k@Mk^T) for 64 tokens
//   odd  blocks: e = sigmoid(v@eW+eb), a = tanh(v@aW+ab) for 64 tokens
// Weight operands wave-uniform (scalar cache). All global stores go through
// an LDS transpose so each store instruction writes 256 contiguous bytes
// (fixes round-4's 4.5x write amplification: 183 MB -> 41 MB).
// ---------------------------------------------------------------------------
__global__ __launch_bounds__(64, 2) void k_token(
    const int* __restrict__ skill, const int* __restrict__ resp,
    const float* __restrict__ k_emb, const float* __restrict__ v_emb,
    const float* __restrict__ Mk,
    const float* __restrict__ eWt, const float* __restrict__ eb,
    const float* __restrict__ aWt, const float* __restrict__ ab,
    float* __restrict__ w_out, float* __restrict__ e_out, float* __restrict__ a_out)
{
    __shared__ float stg[64 * 65];   // 16.6 KB; W-role uses a 64*33 prefix
    const int lane = threadIdx.x;
    const int g = blockIdx.x >> 1;         // token group, 0..1023
    const int tok = g * 64 + lane;
    const int sk = skill[tok];

    if (blockIdx.x & 1) {
        // ---------------- E/A role ----------------
        const int xc = sk + NSKILL * resp[tok];
        float4 vq[16];
        const float4* vp = (const float4*)(v_emb + (size_t)xc * DD);
        #pragma unroll
        for (int q = 0; q < 16; ++q) vq[q] = vp[q];

        // e pass: compute into LDS [token][d] (stride 65 -> conflict-free)
        for (int d = 0; d < DD; d += 2) {
            const float* c0 = eWt + d * DD;
            const float* c1 = c0 + DD;
            float e0 = eb[d], e1 = eb[d + 1];
            #pragma unroll
            for (int q = 0; q < 16; ++q) {
                const float4 vv = vq[q];
                e0 = fmaf(vv.x, c0[4*q+0], e0); e0 = fmaf(vv.y, c0[4*q+1], e0);
                e0 = fmaf(vv.z, c0[4*q+2], e0); e0 = fmaf(vv.w, c0[4*q+3], e0);
                e1 = fmaf(vv.x, c1[4*q+0], e1); e1 = fmaf(vv.y, c1[4*q+1], e1);
                e1 = fmaf(vv.z, c1[4*q+2], e1); e1 = fmaf(vv.w, c1[4*q+3], e1);
            }
            stg[lane * 65 + d]     = sigmoidf_(e0);
            stg[lane * 65 + d + 1] = sigmoidf_(e1);
        }
        __syncthreads();
        {   // coalesced copy-out: 256 B contiguous per iteration
            float* eo = e_out + (size_t)g * 64 * DD;
            #pragma unroll 8
            for (int i = 0; i < 64; ++i) eo[i * DD + lane] = stg[i * 65 + lane];
        }
        __syncthreads();

        // a pass (reuse the same LDS buffer)
        for (int d = 0; d < DD; d += 2) {
            const float* c0 = aWt + d * DD;
            const float* c1 = c0 + DD;
            float a0 = ab[d], a1 = ab[d + 1];
            #pragma unroll
            for (int q = 0; q < 16; ++q) {
                const float4 vv = vq[q];
                a0 = fmaf(vv.x, c0[4*q+0], a0); a0 = fmaf(vv.y, c0[4*q+1], a0);
                a0 = fmaf(vv.z, c0[4*q+2], a0); a0 = fmaf(vv.w, c0[4*q+3], a0);
                a1 = fmaf(vv.x, c1[4*q+0], a1); a1 = fmaf(vv.y, c1[4*q+1], a1);
                a1 = fmaf(vv.z, c1[4*q+2], a1); a1 = fmaf(vv.w, c1[4*q+3], a1);
            }
            stg[lane * 65 + d]     = tanhf_(a0);
            stg[lane * 65 + d + 1] = tanhf_(a1);
        }
        __syncthreads();
        {
            float* ao = a_out + (size_t)g * 64 * DD;
            #pragma unroll 8
            for (int i = 0; i < 64; ++i) ao[i * DD + lane] = stg[i * 65 + lane];
        }
    } else {
        // ---------------- W role ----------------
        float4 kq[16];
        const float4* kp = (const float4*)(k_emb + (size_t)sk * DD);
        #pragma unroll
        for (int q = 0; q < 16; ++q) kq[q] = kp[q];

        float lg[MM];
        #pragma unroll
        for (int m = 0; m < MM; ++m) {
            const float* mk = Mk + m * DD;
            float a0 = 0.f, a1 = 0.f, a2 = 0.f, a3 = 0.f;
            #pragma unroll
            for (int q = 0; q < 16; ++q) {
                const float4 kv = kq[q];
                a0 = fmaf(kv.x, mk[4*q+0], a0);
                a1 = fmaf(kv.y, mk[4*q+1], a1);
                a2 = fmaf(kv.z, mk[4*q+2], a2);
                a3 = fmaf(kv.w, mk[4*q+3], a3);
            }
            lg[m] = (a0 + a1) + (a2 + a3);
        }
        float mx = lg[0];
        #pragma unroll
        for (int m = 1; m < MM; ++m) mx = fmaxf(mx, lg[m]);
        float sm = 0.f;
        #pragma unroll
        for (int m = 0; m < MM; ++m) { lg[m] = __expf(lg[m] - mx); sm += lg[m]; }
        const float inv = 1.f / sm;

        // stage [token][m] at stride 33 (conflict-free), store coalesced
        #pragma unroll
        for (int m = 0; m < MM; ++m) stg[lane * 33 + m] = lg[m] * inv;
        __syncthreads();
        float* wo = w_out + (size_t)g * 64 * MM;
        #pragma unroll 8
        for (int i = 0; i < 32; ++i) {
            const int idx = i * 64 + lane;                 // 2048 floats
            wo[idx] = stg[(idx >> 5) * 33 + (idx & 31)];
        }
    }
}

// ---------------------------------------------------------------------------
// Kernel 2 (scan pass 1): per (b, chunk) compose 32 steps into (Abar, Bbar).
// launch_bounds min-waves=2 -> 256-VGPR cap: keeps Ab/Bb in registers
// (round-4 compiled to VGPR=48 -> spilled the 64 accumulators).
// ---------------------------------------------------------------------------
__global__ __launch_bounds__(64, 2) void k_pass1(
    const float* __restrict__ w, const float* __restrict__ mask,
    const float* __restrict__ e, const float* __restrict__ a,
    float* __restrict__ Abar, float* __restrict__ Bbar)
{
    __shared__ float4 wl[LL * MM / 4];
    const int lane = threadIdx.x;
    const int b = blockIdx.x / CC;
    const int c = blockIdx.x % CC;
    const int t0 = c * LL;

    const float4* wg = (const float4*)(w + (size_t)(b * SS + t0) * MM);
    #pragma unroll
    for (int u = 0; u < 4; ++u) {
        const int q4 = lane + 64 * u;
        const int j = q4 >> 3;
        const float s = (mask[b * SS + t0 + j] == 1.f) ? 1.f : 0.f;
        float4 wq = wg[q4];
        wq.x *= s; wq.y *= s; wq.z *= s; wq.w *= s;
        wl[q4] = wq;
    }
    __syncthreads();

    float Ab[MM], Bb[MM];
    #pragma unroll
    for (int i = 0; i < MM; ++i) { Ab[i] = 1.f; Bb[i] = 0.f; }

    const float* ep = e + (size_t)(b * SS + t0) * DD + lane;
    const float* ap = a + (size_t)(b * SS + t0) * DD + lane;
    for (int j = 0; j < LL; ++j) {
        const float ed = ep[j * DD];
        const float ad = ap[j * DD];
        const float4* wlj = wl + j * 8;
        #pragma unroll
        for (int u = 0; u < 8; ++u) {
            const float4 wq = wlj[u];
            float t1;
            t1 = fmaf(-wq.x, ed, 1.f); Ab[4*u+0] *= t1; Bb[4*u+0] = fmaf(Bb[4*u+0], t1, wq.x * ad);
            t1 = fmaf(-wq.y, ed, 1.f); Ab[4*u+1] *= t1; Bb[4*u+1] = fmaf(Bb[4*u+1], t1, wq.y * ad);
            t1 = fmaf(-wq.z, ed, 1.f); Ab[4*u+2] *= t1; Bb[4*u+2] = fmaf(Bb[4*u+2], t1, wq.z * ad);
            t1 = fmaf(-wq.w, ed, 1.f); Ab[4*u+3] *= t1; Bb[4*u+3] = fmaf(Bb[4*u+3], t1, wq.w * ad);
        }
    }
    float* Ao = Abar + (size_t)blockIdx.x * MM * DD + lane;
    float* Bo = Bbar + (size_t)blockIdx.x * MM * DD + lane;
    #pragma unroll
    for (int i = 0; i < MM; ++i) { Ao[i * DD] = Ab[i]; Bo[i * DD] = Bb[i]; }
}

// ---------------------------------------------------------------------------
// Kernel 3 (scan pass 2): sequential over 64 chunks, parallel over B*M*D.
// Writes chunk-start states IN PLACE into Bbar (read before overwrite).
// ---------------------------------------------------------------------------
__global__ __launch_bounds__(256, 2) void k_pass2(
    const float* __restrict__ Abar, float* __restrict__ Bbar_cst,
    const float* __restrict__ Mv0)
{
    const int idx = blockIdx.x * 256 + threadIdx.x;   // over B*M*D = 65536
    const int b = idx >> 11;
    const int md = idx & 2047;
    float s = Mv0[md];
    for (int c = 0; c < CC; ++c) {
        const int off = ((b * CC + c) << 11) + md;
        const float sa = Abar[off];
        const float sb = Bbar_cst[off];
        Bbar_cst[off] = s;           // cstate[b,c] = state at chunk start
        s = fmaf(s, sa, sb);
    }
}

// ---------------------------------------------------------------------------
// Kernel 4 (scan pass 3): replay each chunk from cstate (=Bbar), emit
// read[b, t+1, d] = sum_m w[b,t+1,m] * Mv_after_t[m,d].
// ---------------------------------------------------------------------------
__global__ __launch_bounds__(64, 2) void k_pass3(
    const float* __restrict__ w, const float* __restrict__ mask,
    const float* __restrict__ e, const float* __restrict__ a,
    const float* __restrict__ cstate, float* __restrict__ readv)
{
    __shared__ float4 wl[LL * MM / 4];
    __shared__ float4 wn[LL * MM / 4];
    const int lane = threadIdx.x;
    const int b = blockIdx.x / CC;
    const int c = blockIdx.x % CC;
    const int t0 = c * LL;
    const bool last = (c == CC - 1);

    const float4* wg  = (const float4*)(w + (size_t)(b * SS + t0) * MM);
    const float4* wg2 = (const float4*)(w + (size_t)(b * SS + t0 + 1) * MM);
    #pragma unroll
    for (int u = 0; u < 4; ++u) {
        const int q4 = lane + 64 * u;
        const int j = q4 >> 3;
        const float s = (mask[b * SS + t0 + j] == 1.f) ? 1.f : 0.f;
        float4 wq = wg[q4];
        wq.x *= s; wq.y *= s; wq.z *= s; wq.w *= s;
        wl[q4] = wq;
        float4 wq2;
        if (last && q4 >= 248) wq2 = make_float4(0.f, 0.f, 0.f, 0.f);
        else                   wq2 = wg2[q4];
        wn[q4] = wq2;
    }
    __syncthreads();

    float Mv[MM];
    const float* cs = cstate + (size_t)blockIdx.x * MM * DD + lane;
    #pragma unroll
    for (int i = 0; i < MM; ++i) Mv[i] = cs[i * DD];

    const float* ep = e + (size_t)(b * SS + t0) * DD + lane;
    const float* ap = a + (size_t)(b * SS + t0) * DD + lane;
    float* ro = readv + (size_t)(b * SS + t0 + 1) * DD + lane;
    for (int j = 0; j < LL; ++j) {
        const float ed = ep[j * DD];
        const float ad = ap[j * DD];
        const float4* wlj = wl + j * 8;
        const float4* wnj = wn + j * 8;
        float r0 = 0.f, r1 = 0.f, r2 = 0.f, r3 = 0.f;
        #pragma unroll
        for (int u = 0; u < 8; ++u) {
            const float4 wq = wlj[u];
            const float4 w2 = wnj[u];
            float t1;
            t1 = fmaf(-wq.x, ed, 1.f); Mv[4*u+0] = fmaf(Mv[4*u+0], t1, wq.x * ad); r0 = fmaf(w2.x, Mv[4*u+0], r0);
            t1 = fmaf(-wq.y, ed, 1.f); Mv[4*u+1] = fmaf(Mv[4*u+1], t1, wq.y * ad); r1 = fmaf(w2.y, Mv[4*u+1], r1);
            t1 = fmaf(-wq.z, ed, 1.f); Mv[4*u+2] = fmaf(Mv[4*u+2], t1, wq.z * ad); r2 = fmaf(w2.z, Mv[4*u+2], r2);
            t1 = fmaf(-wq.w, ed, 1.f); Mv[4*u+3] = fmaf(Mv[4*u+3], t1, wq.w * ad); r3 = fmaf(w2.w, Mv[4*u+3], r3);
        }
        if (!(last && j == LL - 1))
            ro[j * DD] = (r0 + r1) + (r2 + r3);
    }
}

// ---------------------------------------------------------------------------
// Kernel 5: lane = output index. fW columns (fWt rows) are scalar operands;
// read/k rows in registers; out store is lane-contiguous (coalesced).
// min-waves=2 -> 256-VGPR cap (needs ~140 live regs; avoid round-4-style clamp).
// ---------------------------------------------------------------------------
__global__ __launch_bounds__(256, 2) void k_final(
    const float* __restrict__ readv, const int* __restrict__ skill,
    const float* __restrict__ k_emb,
    const float* __restrict__ fWt, const float* __restrict__ fb,
    const float* __restrict__ pW, const float* __restrict__ pb,
    float* __restrict__ out)
{
    const int o = blockIdx.x * 256 + threadIdx.x;   // grid 256 -> 65536 lanes
    const bool valid = o < BB * (SS - 1);
    const int oc = valid ? o : 0;
    const int b = oc / (SS - 1);
    const int s = oc - b * (SS - 1) + 1;            // 1..2047
    const size_t tok = (size_t)b * SS + s;

    float4 rq[16], kq[16];
    const float4* rp = (const float4*)(readv + tok * DD);
    const float4* kp = (const float4*)(k_emb + (size_t)skill[tok] * DD);
    #pragma unroll
    for (int q = 0; q < 16; ++q) { rq[q] = rp[q]; kq[q] = kp[q]; }

    float pacc = 0.f;
    for (int d = 0; d < DD; d += 2) {
        const float* c0 = fWt + d * 128;
        const float* c1 = c0 + 128;
        float f0 = fb[d], f1 = fb[d + 1];
        #pragma unroll
        for (int q = 0; q < 16; ++q) {
            const float4 rv = rq[q];
            f0 = fmaf(rv.x, c0[4*q+0], f0); f0 = fmaf(rv.y, c0[4*q+1], f0);
            f0 = fmaf(rv.z, c0[4*q+2], f0); f0 = fmaf(rv.w, c0[4*q+3], f0);
            f1 = fmaf(rv.x, c1[4*q+0], f1); f1 = fmaf(rv.y, c1[4*q+1], f1);
            f1 = fmaf(rv.z, c1[4*q+2], f1); f1 = fmaf(rv.w, c1[4*q+3], f1);
        }
        #pragma unroll
        for (int q = 0; q < 16; ++q) {
            const float4 kv = kq[q];
            f0 = fmaf(kv.x, c0[64+4*q+0], f0); f0 = fmaf(kv.y, c0[64+4*q+1], f0);
            f0 = fmaf(kv.z, c0[64+4*q+2], f0); f0 = fmaf(kv.w, c0[64+4*q+3], f0);
            f1 = fmaf(kv.x, c1[64+4*q+0], f1); f1 = fmaf(kv.y, c1[64+4*q+1], f1);
            f1 = fmaf(kv.z, c1[64+4*q+2], f1); f1 = fmaf(kv.w, c1[64+4*q+3], f1);
        }
        pacc = fmaf(tanhf_(f0), pW[d], pacc);
        pacc = fmaf(tanhf_(f1), pW[d + 1], pacc);
    }
    if (valid) out[o] = pacc + pb[0];
}

// ---------------------------------------------------------------------------
extern "C" void kernel_launch(void* const* d_in, const int* in_sizes, int n_in,
                              void* d_out, int out_size, void* d_ws, size_t ws_size,
                              hipStream_t stream)
{
    const int*   response = (const int*)d_in[1];
    const int*   skill    = (const int*)d_in[2];
    const float* mask     = (const float*)d_in[3];
    const float* k_emb    = (const float*)d_in[4];
    const float* v_emb    = (const float*)d_in[5];
    const float* Mk       = (const float*)d_in[6];
    const float* Mv0      = (const float*)d_in[7];
    const float* eW       = (const float*)d_in[8];
    const float* ebias    = (const float*)d_in[9];
    const float* aW       = (const float*)d_in[10];
    const float* abias    = (const float*)d_in[11];
    const float* fW       = (const float*)d_in[12];
    const float* fbias    = (const float*)d_in[13];
    const float* pW       = (const float*)d_in[14];
    const float* pbias    = (const float*)d_in[15];
    float* out = (float*)d_out;

    // workspace layout (floats); total 23,085,056 floats = 88.06 MiB
    float* ws    = (float*)d_ws;
    float* w_    = ws;                               // B*S*M   = 2,097,152
    float* e_    = w_    + (size_t)BB * SS * MM;     // B*S*D   = 4,194,304
    float* a_    = e_    + (size_t)BB * SS * DD;
    float* Abar  = a_    + (size_t)BB * SS * DD;     // B*C*M*D = 4,194,304
    float* Bbar  = Abar  + (size_t)BB * CC * MM * DD; // doubles as cstate
    float* readv = Bbar  + (size_t)BB * CC * MM * DD; // B*S*D (row s=0 unused)
    float* eWt   = readv + (size_t)BB * SS * DD;     // 4096
    float* aWt   = eWt   + DD * DD;                  // 4096
    float* fWt   = aWt   + DD * DD;                  // 8192

    k_prep <<<32,   256, 0, stream>>>(eW, aW, fW, eWt, aWt, fWt);
    k_token<<<2048,  64, 0, stream>>>(skill, response, k_emb, v_emb, Mk,
                                      eWt, ebias, aWt, abias, w_, e_, a_);
    k_pass1<<<BB * CC, 64, 0, stream>>>(w_, mask, e_, a_, Abar, Bbar);
    k_pass2<<<256,  256, 0, stream>>>(Abar, Bbar, Mv0);
    k_pass3<<<BB * CC, 64, 0, stream>>>(w_, mask, e_, a_, Bbar, readv);
    k_final<<<256,  256, 0, stream>>>(readv, skill, k_emb, fWt, fbias,
                                      pW, pbias, out);
}

// Round 6
// 232.083 us; speedup vs baseline: 1.6480x; 1.2416x over previous
//
#include <hip/hip_runtime.h>
#include <hip/hip_bf16.h>
#include <math.h>

// Problem constants (fixed by the reference)
#define BB 32      // batch
#define SS 2048    // seq len
#define DD 64      // dim_s
#define MM 32      // size_m
#define NSKILL 4096
#define CC 64      // scan chunks
#define LL 32      // chunk length = SS/CC
#define NOUT (BB * (SS - 1))   // 65504

__device__ __forceinline__ float sigmoidf_(float x) {
    return 1.f / (1.f + __expf(-x));
}
__device__ __forceinline__ float tanhf_(float x) {
    float t = __expf(-2.f * fabsf(x));
    float r = (1.f - t) / (1.f + t);
    return copysignf(r, x);
}

// ---------------------------------------------------------------------------
// Kernel 0: transpose weights (eWt/aWt [d][i] 64x64, fWt [d][i] 64x128) and
// zero-init the output (k_final accumulates with atomics).
// ---------------------------------------------------------------------------
__global__ __launch_bounds__(256) void k_prep(
    const float* __restrict__ eW, const float* __restrict__ aW,
    const float* __restrict__ fW,
    float* __restrict__ eWt, float* __restrict__ aWt, float* __restrict__ fWt,
    float* __restrict__ outz)
{
    const int t = blockIdx.x * 256 + threadIdx.x;   // grid 32*256 = 8192
    if (t < DD * DD) {
        const int i = t >> 6, d = t & 63;
        eWt[d * DD + i] = eW[i * DD + d];
        aWt[d * DD + i] = aW[i * DD + d];
    }
    {   // fW is [128][64]
        const int i = t >> 6, d = t & 63;   // t covers 128*64 = 8192
        fWt[d * 128 + i] = fW[i * DD + d];
    }
    for (int i = t; i < NOUT; i += 8192) outz[i] = 0.f;
}

// ---------------------------------------------------------------------------
// Kernel 1 (v4): 5 balanced roles x 1024 token-groups, 64 thr (1 wave), lane=token.
//   role 0: w = softmax(k@Mk^T)            (~2048 FMA/lane)
//   role 1/2: e = sigmoid(v@eW+eb), d-half (~2048 FMA/lane)
//   role 3/4: a = tanh(v@aW+ab),   d-half  (~2048 FMA/lane)
// Weights wave-uniform (scalar cache; half-footprint 8KB fits sL1).
// Stores staged through LDS for full coalescing (keeps WRITE_SIZE ~41 MB).
// ---------------------------------------------------------------------------
__global__ __launch_bounds__(64, 2) void k_token(
    const int* __restrict__ skill, const int* __restrict__ resp,
    const float* __restrict__ k_emb, const float* __restrict__ v_emb,
    const float* __restrict__ Mk,
    const float* __restrict__ eWt, const float* __restrict__ eb,
    const float* __restrict__ aWt, const float* __restrict__ ab,
    float* __restrict__ w_out, float* __restrict__ e_out, float* __restrict__ a_out)
{
    __shared__ float stg[64 * 33];   // 8448 B -> 19 blocks/CU by LDS
    const int lane = threadIdx.x;
    const int role = blockIdx.x % 5;       // interleaved for XCD balance
    const int g    = blockIdx.x / 5;       // token group, 0..1023
    const int tok  = g * 64 + lane;
    const int sk   = skill[tok];

    if (role == 0) {
        // ---------------- W role ----------------
        float4 kq[16];
        const float4* kp = (const float4*)(k_emb + (size_t)sk * DD);
        #pragma unroll
        for (int q = 0; q < 16; ++q) kq[q] = kp[q];

        float lg[MM];
        #pragma unroll
        for (int m = 0; m < MM; ++m) {
            const float* mk = Mk + m * DD;
            float a0 = 0.f, a1 = 0.f, a2 = 0.f, a3 = 0.f;
            #pragma unroll
            for (int q = 0; q < 16; ++q) {
                const float4 kv = kq[q];
                a0 = fmaf(kv.x, mk[4*q+0], a0);
                a1 = fmaf(kv.y, mk[4*q+1], a1);
                a2 = fmaf(kv.z, mk[4*q+2], a2);
                a3 = fmaf(kv.w, mk[4*q+3], a3);
            }
            lg[m] = (a0 + a1) + (a2 + a3);
        }
        float mx = lg[0];
        #pragma unroll
        for (int m = 1; m < MM; ++m) mx = fmaxf(mx, lg[m]);
        float sm = 0.f;
        #pragma unroll
        for (int m = 0; m < MM; ++m) { lg[m] = __expf(lg[m] - mx); sm += lg[m]; }
        const float inv = 1.f / sm;

        #pragma unroll
        for (int m = 0; m < MM; ++m) stg[lane * 33 + m] = lg[m] * inv;
        __syncthreads();
        float* wo = w_out + (size_t)g * 64 * MM;
        #pragma unroll 8
        for (int i = 0; i < 32; ++i) {
            const int idx = i * 64 + lane;                 // 2048 floats
            wo[idx] = stg[(idx >> 5) * 33 + (idx & 31)];
        }
    } else {
        // ---------------- E/A d-half role ----------------
        const bool isE = (role <= 2);
        const int  dh  = (role & 1) ? 0 : 1;   // roles 1,3 -> half 0; 2,4 -> half 1
        const float* Wt   = isE ? eWt : aWt;
        const float* bias = isE ? eb  : ab;
        float*       op   = isE ? e_out : a_out;

        const int xc = sk + NSKILL * resp[tok];
        float4 vq[16];
        const float4* vp = (const float4*)(v_emb + (size_t)xc * DD);
        #pragma unroll
        for (int q = 0; q < 16; ++q) vq[q] = vp[q];

        const int d0 = dh * 32;
        for (int dd = 0; dd < 32; dd += 2) {
            const float* c0 = Wt + (d0 + dd) * DD;
            const float* c1 = c0 + DD;
            float x0 = bias[d0 + dd], x1 = bias[d0 + dd + 1];
            #pragma unroll
            for (int q = 0; q < 16; ++q) {
                const float4 vv = vq[q];
                x0 = fmaf(vv.x, c0[4*q+0], x0); x0 = fmaf(vv.y, c0[4*q+1], x0);
                x0 = fmaf(vv.z, c0[4*q+2], x0); x0 = fmaf(vv.w, c0[4*q+3], x0);
                x1 = fmaf(vv.x, c1[4*q+0], x1); x1 = fmaf(vv.y, c1[4*q+1], x1);
                x1 = fmaf(vv.z, c1[4*q+2], x1); x1 = fmaf(vv.w, c1[4*q+3], x1);
            }
            if (isE) { x0 = sigmoidf_(x0); x1 = sigmoidf_(x1); }
            else     { x0 = tanhf_(x0);    x1 = tanhf_(x1);    }
            stg[lane * 33 + dd]     = x0;
            stg[lane * 33 + dd + 1] = x1;
        }
        __syncthreads();
        #pragma unroll 8
        for (int i = 0; i < 32; ++i) {        // 2048 floats, 128B contiguous/half-wave
            const int idx = i * 64 + lane;
            const int row = idx >> 5, col = idx & 31;
            op[(size_t)(g * 64 + row) * DD + d0 + col] = stg[row * 33 + col];
        }
    }
}

// ---------------------------------------------------------------------------
// Kernel 2 (scan pass 1, m-split): 2 blocks per (b,chunk); each composes 32
// steps for 16 m-rows. A_t[m,d]=1-w~[m]e[d], B_t[m,d]=w~[m]a[d]. Outputs
// disjoint -> no atomics. 4096 waves.
// ---------------------------------------------------------------------------
__global__ __launch_bounds__(64, 4) void k_pass1(
    const float* __restrict__ w, const float* __restrict__ mask,
    const float* __restrict__ e, const float* __restrict__ a,
    float* __restrict__ Abar, float* __restrict__ Bbar)
{
    __shared__ float4 wl[LL * 16 / 4];   // 128 float4: masked w, 16 m-cols
    const int lane = threadIdx.x;
    const int bc = blockIdx.x >> 1;
    const int mh = blockIdx.x & 1;
    const int b = bc / CC;
    const int c = bc % CC;
    const int t0 = c * LL;

    const float4* wg = (const float4*)(w + (size_t)(b * SS + t0) * MM);
    #pragma unroll
    for (int u = 0; u < 2; ++u) {
        const int q4 = u * 64 + lane;        // 0..127
        const int j = q4 >> 2;               // token row
        const int q = q4 & 3;                // float4 within the m-half
        const float s = (mask[b * SS + t0 + j] == 1.f) ? 1.f : 0.f;
        float4 wq = wg[j * 8 + mh * 4 + q];
        wq.x *= s; wq.y *= s; wq.z *= s; wq.w *= s;
        wl[q4] = wq;
    }
    __syncthreads();

    float Ab[16], Bb[16];
    #pragma unroll
    for (int i = 0; i < 16; ++i) { Ab[i] = 1.f; Bb[i] = 0.f; }

    const float* ep = e + (size_t)(b * SS + t0) * DD + lane;
    const float* ap = a + (size_t)(b * SS + t0) * DD + lane;
    for (int j = 0; j < LL; ++j) {
        const float ed = ep[j * DD];
        const float ad = ap[j * DD];
        const float4* wlj = wl + j * 4;
        #pragma unroll
        for (int u = 0; u < 4; ++u) {
            const float4 wq = wlj[u];
            float t1;
            t1 = fmaf(-wq.x, ed, 1.f); Ab[4*u+0] *= t1; Bb[4*u+0] = fmaf(Bb[4*u+0], t1, wq.x * ad);
            t1 = fmaf(-wq.y, ed, 1.f); Ab[4*u+1] *= t1; Bb[4*u+1] = fmaf(Bb[4*u+1], t1, wq.y * ad);
            t1 = fmaf(-wq.z, ed, 1.f); Ab[4*u+2] *= t1; Bb[4*u+2] = fmaf(Bb[4*u+2], t1, wq.z * ad);
            t1 = fmaf(-wq.w, ed, 1.f); Ab[4*u+3] *= t1; Bb[4*u+3] = fmaf(Bb[4*u+3], t1, wq.w * ad);
        }
    }
    float* Ao = Abar + (size_t)bc * MM * DD + (size_t)(mh * 16) * DD + lane;
    float* Bo = Bbar + (size_t)bc * MM * DD + (size_t)(mh * 16) * DD + lane;
    #pragma unroll
    for (int i = 0; i < 16; ++i) { Ao[i * DD] = Ab[i]; Bo[i * DD] = Bb[i]; }
}

// ---------------------------------------------------------------------------
// Kernel 3 (scan pass 2): sequential over 64 chunks, parallel over B*M*D.
// Writes chunk-start states IN PLACE into Bbar (read before overwrite).
// ---------------------------------------------------------------------------
__global__ __launch_bounds__(256, 2) void k_pass2(
    const float* __restrict__ Abar, float* __restrict__ Bbar_cst,
    const float* __restrict__ Mv0)
{
    const int idx = blockIdx.x * 256 + threadIdx.x;   // over B*M*D = 65536
    const int b = idx >> 11;
    const int md = idx & 2047;
    float s = Mv0[md];
    for (int c = 0; c < CC; ++c) {
        const int off = ((b * CC + c) << 11) + md;
        const float sa = Abar[off];
        const float sb = Bbar_cst[off];
        Bbar_cst[off] = s;           // cstate[b,c] = state at chunk start
        s = fmaf(s, sa, sb);
    }
}

// ---------------------------------------------------------------------------
// Kernel 4 (scan pass 3, d-split): 2 blocks per (b,chunk). lane=(m-half, d-off):
// each lane scans Mv[16] for its (16 m) x (its d); read-partials folded across
// m-halves with shfl_xor(32). 4096 waves.
// ---------------------------------------------------------------------------
__global__ __launch_bounds__(64, 4) void k_pass3(
    const float* __restrict__ w, const float* __restrict__ mask,
    const float* __restrict__ e, const float* __restrict__ a,
    const float* __restrict__ cstate, float* __restrict__ readv)
{
    __shared__ float4 wl[LL * MM / 4];   // masked w  (full 32 m)
    __shared__ float4 wn[LL * MM / 4];   // unmasked w, t+1
    const int lane = threadIdx.x;
    const int bc = blockIdx.x >> 1;
    const int dh = blockIdx.x & 1;
    const int b = bc / CC;
    const int c = bc % CC;
    const int t0 = c * LL;
    const bool last = (c == CC - 1);
    const int dof = lane & 31;
    const int mh  = lane >> 5;

    const float4* wg  = (const float4*)(w + (size_t)(b * SS + t0) * MM);
    const float4* wg2 = (const float4*)(w + (size_t)(b * SS + t0 + 1) * MM);
    #pragma unroll
    for (int u = 0; u < 4; ++u) {
        const int q4 = u * 64 + lane;
        const int j = q4 >> 3;
        const float s = (mask[b * SS + t0 + j] == 1.f) ? 1.f : 0.f;
        float4 wq = wg[q4];
        wq.x *= s; wq.y *= s; wq.z *= s; wq.w *= s;
        wl[q4] = wq;
        float4 wq2;
        if (last && q4 >= 248) wq2 = make_float4(0.f, 0.f, 0.f, 0.f);
        else                   wq2 = wg2[q4];
        wn[q4] = wq2;
    }
    __syncthreads();

    float Mv[16];
    const float* cs = cstate + (size_t)bc * MM * DD + (size_t)(mh * 16) * DD
                      + dh * 32 + dof;
    #pragma unroll
    for (int i = 0; i < 16; ++i) Mv[i] = cs[i * DD];

    const float* ep = e + (size_t)(b * SS + t0) * DD + dh * 32 + dof;
    const float* ap = a + (size_t)(b * SS + t0) * DD + dh * 32 + dof;
    float* ro = readv + (size_t)(b * SS + t0 + 1) * DD + dh * 32 + dof;
    for (int j = 0; j < LL; ++j) {
        const float ed = ep[j * DD];
        const float ad = ap[j * DD];
        const float4* wlj = wl + j * 8 + mh * 4;
        const float4* wnj = wn + j * 8 + mh * 4;
        float r0 = 0.f, r1 = 0.f, r2 = 0.f, r3 = 0.f;
        #pragma unroll
        for (int u = 0; u < 4; ++u) {
            const float4 wq = wlj[u];
            const float4 w2 = wnj[u];
            float t1;
            t1 = fmaf(-wq.x, ed, 1.f); Mv[4*u+0] = fmaf(Mv[4*u+0], t1, wq.x * ad); r0 = fmaf(w2.x, Mv[4*u+0], r0);
            t1 = fmaf(-wq.y, ed, 1.f); Mv[4*u+1] = fmaf(Mv[4*u+1], t1, wq.y * ad); r1 = fmaf(w2.y, Mv[4*u+1], r1);
            t1 = fmaf(-wq.z, ed, 1.f); Mv[4*u+2] = fmaf(Mv[4*u+2], t1, wq.z * ad); r2 = fmaf(w2.z, Mv[4*u+2], r2);
            t1 = fmaf(-wq.w, ed, 1.f); Mv[4*u+3] = fmaf(Mv[4*u+3], t1, wq.w * ad); r3 = fmaf(w2.w, Mv[4*u+3], r3);
        }
        float r = (r0 + r1) + (r2 + r3);
        r += __shfl_xor(r, 32);              // fold the two m-halves
        if (mh == 0 && !(last && j == LL - 1))
            ro[j * DD] = r;
    }
}

// ---------------------------------------------------------------------------
// Kernel 5 (d-half split): 2 blocks per 64 outputs; lane = output. Each block
// computes 32 of the 64 tanh(f)-columns and atomically accumulates its
// partial p into out (zero-initialized by k_prep). 2048 waves.
// ---------------------------------------------------------------------------
__global__ __launch_bounds__(64, 2) void k_final(
    const float* __restrict__ readv, const int* __restrict__ skill,
    const float* __restrict__ k_emb,
    const float* __restrict__ fWt, const float* __restrict__ fb,
    const float* __restrict__ pW, const float* __restrict__ pb,
    float* __restrict__ out)
{
    const int lane = threadIdx.x;
    const int o  = (blockIdx.x >> 1) * 64 + lane;
    const int dh = blockIdx.x & 1;
    const bool valid = o < NOUT;
    const int oc = valid ? o : 0;
    const int b = oc / (SS - 1);
    const int s = oc - b * (SS - 1) + 1;            // 1..2047
    const size_t tok = (size_t)b * SS + s;

    float4 rq[16], kq[16];
    const float4* rp = (const float4*)(readv + tok * DD);
    const float4* kp = (const float4*)(k_emb + (size_t)skill[tok] * DD);
    #pragma unroll
    for (int q = 0; q < 16; ++q) { rq[q] = rp[q]; kq[q] = kp[q]; }

    float pacc = 0.f;
    const int d0 = dh * 32;
    for (int dd = 0; dd < 32; dd += 2) {
        const float* c0 = fWt + (d0 + dd) * 128;
        const float* c1 = c0 + 128;
        float f0 = fb[d0 + dd], f1 = fb[d0 + dd + 1];
        #pragma unroll
        for (int q = 0; q < 16; ++q) {
            const float4 rv = rq[q];
            f0 = fmaf(rv.x, c0[4*q+0], f0); f0 = fmaf(rv.y, c0[4*q+1], f0);
            f0 = fmaf(rv.z, c0[4*q+2], f0); f0 = fmaf(rv.w, c0[4*q+3], f0);
            f1 = fmaf(rv.x, c1[4*q+0], f1); f1 = fmaf(rv.y, c1[4*q+1], f1);
            f1 = fmaf(rv.z, c1[4*q+2], f1); f1 = fmaf(rv.w, c1[4*q+3], f1);
        }
        #pragma unroll
        for (int q = 0; q < 16; ++q) {
            const float4 kv = kq[q];
            f0 = fmaf(kv.x, c0[64+4*q+0], f0); f0 = fmaf(kv.y, c0[64+4*q+1], f0);
            f0 = fmaf(kv.z, c0[64+4*q+2], f0); f0 = fmaf(kv.w, c0[64+4*q+3], f0);
            f1 = fmaf(kv.x, c1[64+4*q+0], f1); f1 = fmaf(kv.y, c1[64+4*q+1], f1);
            f1 = fmaf(kv.z, c1[64+4*q+2], f1); f1 = fmaf(kv.w, c1[64+4*q+3], f1);
        }
        pacc = fmaf(tanhf_(f0), pW[d0 + dd], pacc);
        pacc = fmaf(tanhf_(f1), pW[d0 + dd + 1], pacc);
    }
    if (valid) atomicAdd(&out[o], pacc + (dh ? 0.f : pb[0]));
}

// ---------------------------------------------------------------------------
extern "C" void kernel_launch(void* const* d_in, const int* in_sizes, int n_in,
                              void* d_out, int out_size, void* d_ws, size_t ws_size,
                              hipStream_t stream)
{
    const int*   response = (const int*)d_in[1];
    const int*   skill    = (const int*)d_in[2];
    const float* mask     = (const float*)d_in[3];
    const float* k_emb    = (const float*)d_in[4];
    const float* v_emb    = (const float*)d_in[5];
    const float* Mk       = (const float*)d_in[6];
    const float* Mv0      = (const float*)d_in[7];
    const float* eW       = (const float*)d_in[8];
    const float* ebias    = (const float*)d_in[9];
    const float* aW       = (const float*)d_in[10];
    const float* abias    = (const float*)d_in[11];
    const float* fW       = (const float*)d_in[12];
    const float* fbias    = (const float*)d_in[13];
    const float* pW       = (const float*)d_in[14];
    const float* pbias    = (const float*)d_in[15];
    float* out = (float*)d_out;

    // workspace layout (floats); total 23,085,056 floats = 88.06 MiB
    float* ws    = (float*)d_ws;
    float* w_    = ws;                               // B*S*M   = 2,097,152
    float* e_    = w_    + (size_t)BB * SS * MM;     // B*S*D   = 4,194,304
    float* a_    = e_    + (size_t)BB * SS * DD;
    float* Abar  = a_    + (size_t)BB * SS * DD;     // B*C*M*D = 4,194,304
    float* Bbar  = Abar  + (size_t)BB * CC * MM * DD; // doubles as cstate
    float* readv = Bbar  + (size_t)BB * CC * MM * DD; // B*S*D (row s=0 unused)
    float* eWt   = readv + (size_t)BB * SS * DD;     // 4096
    float* aWt   = eWt   + DD * DD;                  // 4096
    float* fWt   = aWt   + DD * DD;                  // 8192

    k_prep <<<32,   256, 0, stream>>>(eW, aW, fW, eWt, aWt, fWt, out);
    k_token<<<5120,  64, 0, stream>>>(skill, response, k_emb, v_emb, Mk,
                                      eWt, ebias, aWt, abias, w_, e_, a_);
    k_pass1<<<BB * CC * 2, 64, 0, stream>>>(w_, mask, e_, a_, Abar, Bbar);
    k_pass2<<<256,  256, 0, stream>>>(Abar, Bbar, Mv0);
    k_pass3<<<BB * CC * 2, 64, 0, stream>>>(w_, mask, e_, a_, Bbar, readv);
    k_final<<<2048,  64, 0, stream>>>(readv, skill, k_emb, fWt, fbias,
                                      pW, pbias, out);
}

// Round 10
// 216.132 us; speedup vs baseline: 1.7696x; 1.0738x over previous
//
#include <hip/hip_runtime.h>
#include <hip/hip_bf16.h>
#include <math.h>

// Problem constants (fixed by the reference)
#define BB 32      // batch
#define SS 2048    // seq len
#define DD 64      // dim_s
#define MM 32      // size_m
#define NSKILL 4096
#define CC 64      // scan chunks
#define LL 32      // chunk length = SS/CC
#define NOUT (BB * (SS - 1))   // 65504

__device__ __forceinline__ float sigmoidf_(float x) {
    return 1.f / (1.f + __expf(-x));
}
__device__ __forceinline__ float tanhf_(float x) {
    float t = __expf(-2.f * fabsf(x));
    float r = (1.f - t) / (1.f + t);
    return copysignf(r, x);
}

// ---------------------------------------------------------------------------
// Kernel 1: w = softmax(k @ Mk^T). 1024 blocks x 256 thr, 64 tokens/block.
// lane = (m, token-half); Mk row m in 64 VGPRs (loaded once, L1-hot);
// k rows staged in LDS, read uniform-per-32-lane-group (2-addr = free).
// Softmax via shfl within the 32-lane m-group. Stores 256B contiguous.
// ---------------------------------------------------------------------------
__global__ __launch_bounds__(256, 2) void k_w(
    const int* __restrict__ skill, const float* __restrict__ k_emb,
    const float* __restrict__ Mk, float* __restrict__ w_out)
{
    __shared__ float kst[64][64];
    const int tid = threadIdx.x;
    const int g = blockIdx.x;
    // stage 64 k-rows: 16 threads x 16B per row, 4 passes
    #pragma unroll
    for (int p = 0; p < 4; ++p) {
        const int r = p * 16 + (tid >> 4);
        const int t = g * 64 + r;
        const float4 kv = ((const float4*)(k_emb + (size_t)skill[t] * DD))[tid & 15];
        *(float4*)&kst[r][(tid & 15) * 4] = kv;
    }
    const int l  = tid & 63;
    const int m  = l & 31;
    const int th = l >> 5;
    const int w  = tid >> 6;
    float4 mk4[16];
    const float4* mkp = (const float4*)(Mk + m * DD);
    #pragma unroll
    for (int q = 0; q < 16; ++q) mk4[q] = mkp[q];
    __syncthreads();

    for (int j = 0; j < 8; ++j) {
        const int tl = w * 16 + j * 2 + th;          // local token 0..63
        const float4* kp = (const float4*)&kst[tl][0];
        float a0 = 0.f, a1 = 0.f, a2 = 0.f, a3 = 0.f;
        #pragma unroll
        for (int q = 0; q < 16; ++q) {
            const float4 kv = kp[q];
            a0 = fmaf(kv.x, mk4[q].x, a0);
            a1 = fmaf(kv.y, mk4[q].y, a1);
            a2 = fmaf(kv.z, mk4[q].z, a2);
            a3 = fmaf(kv.w, mk4[q].w, a3);
        }
        const float lg = (a0 + a1) + (a2 + a3);
        float mx = lg;
        #pragma unroll
        for (int off = 16; off >= 1; off >>= 1) mx = fmaxf(mx, __shfl_xor(mx, off));
        const float ev = __expf(lg - mx);
        float sm = ev;
        #pragma unroll
        for (int off = 16; off >= 1; off >>= 1) sm += __shfl_xor(sm, off);
        w_out[(size_t)(g * 64 + tl) * MM + m] = ev / sm;   // 256B/wave-instr
    }
}

// ---------------------------------------------------------------------------
// Kernel 2: e = sigmoid(v@eW+eb), a = tanh(v@aW+ab), fused over one v row.
// 1024 blocks x 256 thr, 64 tokens/block, 16 tokens/wave. lane = output d;
// eW/aW columns in 128 VGPRs (coalesced loads from ORIGINAL [i][d] layout);
// v rows staged in LDS, broadcast via uniform ds_read_b128.
// 16 LDS reads feed 128 FMAs per token -> compute-bound.
// ---------------------------------------------------------------------------
__global__ __launch_bounds__(256, 2) void k_ea(
    const int* __restrict__ skill, const int* __restrict__ resp,
    const float* __restrict__ v_emb,
    const float* __restrict__ eW, const float* __restrict__ eb,
    const float* __restrict__ aW, const float* __restrict__ ab,
    float* __restrict__ e_out, float* __restrict__ a_out)
{
    __shared__ float vst[64][64];
    const int tid = threadIdx.x;
    const int g = blockIdx.x;
    #pragma unroll
    for (int p = 0; p < 4; ++p) {
        const int r = p * 16 + (tid >> 4);
        const int t = g * 64 + r;
        const int xc = skill[t] + NSKILL * resp[t];
        const float4 vv = ((const float4*)(v_emb + (size_t)xc * DD))[tid & 15];
        *(float4*)&vst[r][(tid & 15) * 4] = vv;
    }
    const int l = tid & 63;
    const int w = tid >> 6;
    float ew[64], aw[64];
    #pragma unroll
    for (int i = 0; i < 64; ++i) ew[i] = eW[i * DD + l];   // coalesced
    #pragma unroll
    for (int i = 0; i < 64; ++i) aw[i] = aW[i * DD + l];
    const float ebd = eb[l], abd = ab[l];
    __syncthreads();

    for (int j = 0; j < 16; ++j) {
        const int tl = w * 16 + j;
        const float4* vp = (const float4*)&vst[tl][0];
        float e0 = ebd, e1 = 0.f, e2 = 0.f, e3 = 0.f;
        float x0 = abd, x1 = 0.f, x2 = 0.f, x3 = 0.f;
        #pragma unroll
        for (int q = 0; q < 16; ++q) {
            const float4 vv = vp[q];                  // broadcast read
            e0 = fmaf(vv.x, ew[4*q+0], e0);
            e1 = fmaf(vv.y, ew[4*q+1], e1);
            e2 = fmaf(vv.z, ew[4*q+2], e2);
            e3 = fmaf(vv.w, ew[4*q+3], e3);
            x0 = fmaf(vv.x, aw[4*q+0], x0);
            x1 = fmaf(vv.y, aw[4*q+1], x1);
            x2 = fmaf(vv.z, aw[4*q+2], x2);
            x3 = fmaf(vv.w, aw[4*q+3], x3);
        }
        const size_t t = (size_t)(g * 64 + tl);
        e_out[t * DD + l] = sigmoidf_((e0 + e1) + (e2 + e3));  // 256B/instr
        a_out[t * DD + l] = tanhf_((x0 + x1) + (x2 + x3));
    }
}

// ---------------------------------------------------------------------------
// Kernel 3 (scan pass 1, m-split): 2 blocks per (b,chunk); each composes 32
// steps for 16 m-rows. Outputs disjoint.
// ---------------------------------------------------------------------------
__global__ __launch_bounds__(64, 4) void k_pass1(
    const float* __restrict__ w, const float* __restrict__ mask,
    const float* __restrict__ e, const float* __restrict__ a,
    float* __restrict__ Abar, float* __restrict__ Bbar)
{
    __shared__ float4 wl[LL * 16 / 4];   // 128 float4: masked w, 16 m-cols
    const int lane = threadIdx.x;
    const int bc = blockIdx.x >> 1;
    const int mh = blockIdx.x & 1;
    const int b = bc / CC;
    const int c = bc % CC;
    const int t0 = c * LL;

    const float4* wg = (const float4*)(w + (size_t)(b * SS + t0) * MM);
    #pragma unroll
    for (int u = 0; u < 2; ++u) {
        const int q4 = u * 64 + lane;        // 0..127
        const int j = q4 >> 2;               // token row
        const int q = q4 & 3;                // float4 within the m-half
        const float s = (mask[b * SS + t0 + j] == 1.f) ? 1.f : 0.f;
        float4 wq = wg[j * 8 + mh * 4 + q];
        wq.x *= s; wq.y *= s; wq.z *= s; wq.w *= s;
        wl[q4] = wq;
    }
    __syncthreads();

    float Ab[16], Bb[16];
    #pragma unroll
    for (int i = 0; i < 16; ++i) { Ab[i] = 1.f; Bb[i] = 0.f; }

    const float* ep = e + (size_t)(b * SS + t0) * DD + lane;
    const float* ap = a + (size_t)(b * SS + t0) * DD + lane;
    for (int j = 0; j < LL; ++j) {
        const float ed = ep[j * DD];
        const float ad = ap[j * DD];
        const float4* wlj = wl + j * 4;
        #pragma unroll
        for (int u = 0; u < 4; ++u) {
            const float4 wq = wlj[u];
            float t1;
            t1 = fmaf(-wq.x, ed, 1.f); Ab[4*u+0] *= t1; Bb[4*u+0] = fmaf(Bb[4*u+0], t1, wq.x * ad);
            t1 = fmaf(-wq.y, ed, 1.f); Ab[4*u+1] *= t1; Bb[4*u+1] = fmaf(Bb[4*u+1], t1, wq.y * ad);
            t1 = fmaf(-wq.z, ed, 1.f); Ab[4*u+2] *= t1; Bb[4*u+2] = fmaf(Bb[4*u+2], t1, wq.z * ad);
            t1 = fmaf(-wq.w, ed, 1.f); Ab[4*u+3] *= t1; Bb[4*u+3] = fmaf(Bb[4*u+3], t1, wq.w * ad);
        }
    }
    float* Ao = Abar + (size_t)bc * MM * DD + (size_t)(mh * 16) * DD + lane;
    float* Bo = Bbar + (size_t)bc * MM * DD + (size_t)(mh * 16) * DD + lane;
    #pragma unroll
    for (int i = 0; i < 16; ++i) { Ao[i * DD] = Ab[i]; Bo[i * DD] = Bb[i]; }
}

// ---------------------------------------------------------------------------
// Kernel 4 (scan pass 2): sequential over 64 chunks, parallel over B*M*D.
// Writes chunk-start states IN PLACE into Bbar (read before overwrite).
// ---------------------------------------------------------------------------
__global__ __launch_bounds__(256, 2) void k_pass2(
    const float* __restrict__ Abar, float* __restrict__ Bbar_cst,
    const float* __restrict__ Mv0)
{
    const int idx = blockIdx.x * 256 + threadIdx.x;   // over B*M*D = 65536
    const int b = idx >> 11;
    const int md = idx & 2047;
    float s = Mv0[md];
    for (int c = 0; c < CC; ++c) {
        const int off = ((b * CC + c) << 11) + md;
        const float sa = Abar[off];
        const float sb = Bbar_cst[off];
        Bbar_cst[off] = s;           // cstate[b,c] = state at chunk start
        s = fmaf(s, sa, sb);
    }
}

// ---------------------------------------------------------------------------
// Kernel 5 (scan pass 3, d-split): 2 blocks per (b,chunk). lane=(m-half, d-off);
// Mv[16]/lane; read partials folded across m-halves with shfl_xor(32).
// ---------------------------------------------------------------------------
__global__ __launch_bounds__(64, 4) void k_pass3(
    const float* __restrict__ w, const float* __restrict__ mask,
    const float* __restrict__ e, const float* __restrict__ a,
    const float* __restrict__ cstate, float* __restrict__ readv)
{
    __shared__ float4 wl[LL * MM / 4];   // masked w  (full 32 m)
    __shared__ float4 wn[LL * MM / 4];   // unmasked w, t+1
    const int lane = threadIdx.x;
    const int bc = blockIdx.x >> 1;
    const int dh = blockIdx.x & 1;
    const int b = bc / CC;
    const int c = bc % CC;
    const int t0 = c * LL;
    const bool last = (c == CC - 1);
    const int dof = lane & 31;
    const int mh  = lane >> 5;

    const float4* wg  = (const float4*)(w + (size_t)(b * SS + t0) * MM);
    const float4* wg2 = (const float4*)(w + (size_t)(b * SS + t0 + 1) * MM);
    #pragma unroll
    for (int u = 0; u < 4; ++u) {
        const int q4 = u * 64 + lane;
        const int j = q4 >> 3;
        const float s = (mask[b * SS + t0 + j] == 1.f) ? 1.f : 0.f;
        float4 wq = wg[q4];
        wq.x *= s; wq.y *= s; wq.z *= s; wq.w *= s;
        wl[q4] = wq;
        float4 wq2;
        if (last && q4 >= 248) wq2 = make_float4(0.f, 0.f, 0.f, 0.f);
        else                   wq2 = wg2[q4];
        wn[q4] = wq2;
    }
    __syncthreads();

    float Mv[16];
    const float* cs = cstate + (size_t)bc * MM * DD + (size_t)(mh * 16) * DD
                      + dh * 32 + dof;
    #pragma unroll
    for (int i = 0; i < 16; ++i) Mv[i] = cs[i * DD];

    const float* ep = e + (size_t)(b * SS + t0) * DD + dh * 32 + dof;
    const float* ap = a + (size_t)(b * SS + t0) * DD + dh * 32 + dof;
    float* ro = readv + (size_t)(b * SS + t0 + 1) * DD + dh * 32 + dof;
    for (int j = 0; j < LL; ++j) {
        const float ed = ep[j * DD];
        const float ad = ap[j * DD];
        const float4* wlj = wl + j * 8 + mh * 4;
        const float4* wnj = wn + j * 8 + mh * 4;
        float r0 = 0.f, r1 = 0.f, r2 = 0.f, r3 = 0.f;
        #pragma unroll
        for (int u = 0; u < 4; ++u) {
            const float4 wq = wlj[u];
            const float4 w2 = wnj[u];
            float t1;
            t1 = fmaf(-wq.x, ed, 1.f); Mv[4*u+0] = fmaf(Mv[4*u+0], t1, wq.x * ad); r0 = fmaf(w2.x, Mv[4*u+0], r0);
            t1 = fmaf(-wq.y, ed, 1.f); Mv[4*u+1] = fmaf(Mv[4*u+1], t1, wq.y * ad); r1 = fmaf(w2.y, Mv[4*u+1], r1);
            t1 = fmaf(-wq.z, ed, 1.f); Mv[4*u+2] = fmaf(Mv[4*u+2], t1, wq.z * ad); r2 = fmaf(w2.z, Mv[4*u+2], r2);
            t1 = fmaf(-wq.w, ed, 1.f); Mv[4*u+3] = fmaf(Mv[4*u+3], t1, wq.w * ad); r3 = fmaf(w2.w, Mv[4*u+3], r3);
        }
        float r = (r0 + r1) + (r2 + r3);
        r += __shfl_xor(r, 32);              // fold the two m-halves
        if (mh == 0 && !(last && j == LL - 1))
            ro[j * DD] = r;
    }
}

// ---------------------------------------------------------------------------
// Kernel 6: p = tanh([read,k]@fW+fb)@pW + pb. 1024 blocks x 256 thr,
// 64 outputs/block. lane = f-column d; fW column in 128 VGPRs (coalesced from
// original [i][d] layout); read/k rows staged in LDS, broadcast reads;
// p via full-wave shfl reduce, staged in LDS, stored coalesced.
// ---------------------------------------------------------------------------
__global__ __launch_bounds__(256, 2) void k_final(
    const float* __restrict__ readv, const int* __restrict__ skill,
    const float* __restrict__ k_emb,
    const float* __restrict__ fW, const float* __restrict__ fb,
    const float* __restrict__ pW, const float* __restrict__ pb,
    float* __restrict__ out)
{
    __shared__ float rst[64][64];
    __shared__ float kst[64][64];
    __shared__ float pbuf[64];
    const int tid = threadIdx.x;
    const int g = blockIdx.x;
    #pragma unroll
    for (int p = 0; p < 4; ++p) {
        const int r = p * 16 + (tid >> 4);
        int o = g * 64 + r;
        if (o >= NOUT) o = 0;                       // clamp (last block only)
        const int b = o / (SS - 1);
        const int s = o - b * (SS - 1) + 1;         // 1..2047
        const size_t tok = (size_t)b * SS + s;
        const int q = tid & 15;
        *(float4*)&rst[r][q * 4] = ((const float4*)(readv + tok * DD))[q];
        *(float4*)&kst[r][q * 4] = ((const float4*)(k_emb + (size_t)skill[tok] * DD))[q];
    }
    const int l = tid & 63;
    const int w = tid >> 6;
    float fw[128];
    #pragma unroll
    for (int i = 0; i < 128; ++i) fw[i] = fW[i * DD + l];   // coalesced
    const float fbd = fb[l], pwd = pW[l];
    __syncthreads();

    for (int j = 0; j < 16; ++j) {
        const int tl = w * 16 + j;
        const float4* rp = (const float4*)&rst[tl][0];
        const float4* kp = (const float4*)&kst[tl][0];
        float f0 = fbd, f1 = 0.f, f2 = 0.f, f3 = 0.f;
        #pragma unroll
        for (int q = 0; q < 16; ++q) {
            const float4 rv = rp[q];
            f0 = fmaf(rv.x, fw[4*q+0], f0);
            f1 = fmaf(rv.y, fw[4*q+1], f1);
            f2 = fmaf(rv.z, fw[4*q+2], f2);
            f3 = fmaf(rv.w, fw[4*q+3], f3);
        }
        #pragma unroll
        for (int q = 0; q < 16; ++q) {
            const float4 kv = kp[q];
            f0 = fmaf(kv.x, fw[64+4*q+0], f0);
            f1 = fmaf(kv.y, fw[64+4*q+1], f1);
            f2 = fmaf(kv.z, fw[64+4*q+2], f2);
            f3 = fmaf(kv.w, fw[64+4*q+3], f3);
        }
        float pv = tanhf_((f0 + f1) + (f2 + f3)) * pwd;
        #pragma unroll
        for (int off = 32; off >= 1; off >>= 1) pv += __shfl_xor(pv, off);
        if (l == 0) pbuf[tl] = pv;
    }
    __syncthreads();
    if (tid < 64) {
        const int o = g * 64 + tid;
        if (o < NOUT) out[o] = pbuf[tid] + pb[0];
    }
}

// ---------------------------------------------------------------------------
extern "C" void kernel_launch(void* const* d_in, const int* in_sizes, int n_in,
                              void* d_out, int out_size, void* d_ws, size_t ws_size,
                              hipStream_t stream)
{
    const int*   response = (const int*)d_in[1];
    const int*   skill    = (const int*)d_in[2];
    const float* mask     = (const float*)d_in[3];
    const float* k_emb    = (const float*)d_in[4];
    const float* v_emb    = (const float*)d_in[5];
    const float* Mk       = (const float*)d_in[6];
    const float* Mv0      = (const float*)d_in[7];
    const float* eW       = (const float*)d_in[8];
    const float* ebias    = (const float*)d_in[9];
    const float* aW       = (const float*)d_in[10];
    const float* abias    = (const float*)d_in[11];
    const float* fW       = (const float*)d_in[12];
    const float* fbias    = (const float*)d_in[13];
    const float* pW       = (const float*)d_in[14];
    const float* pbias    = (const float*)d_in[15];
    float* out = (float*)d_out;

    // workspace layout (floats); total 23,068,672 floats = 88.0 MiB
    float* ws    = (float*)d_ws;
    float* w_    = ws;                               // B*S*M   = 2,097,152
    float* e_    = w_    + (size_t)BB * SS * MM;     // B*S*D   = 4,194,304
    float* a_    = e_    + (size_t)BB * SS * DD;
    float* Abar  = a_    + (size_t)BB * SS * DD;     // B*C*M*D = 4,194,304
    float* Bbar  = Abar  + (size_t)BB * CC * MM * DD; // doubles as cstate
    float* readv = Bbar  + (size_t)BB * CC * MM * DD; // B*S*D (row s=0 unused)

    k_w    <<<1024, 256, 0, stream>>>(skill, k_emb, Mk, w_);
    k_ea   <<<1024, 256, 0, stream>>>(skill, response, v_emb,
                                      eW, ebias, aW, abias, e_, a_);
    k_pass1<<<BB * CC * 2, 64, 0, stream>>>(w_, mask, e_, a_, Abar, Bbar);
    k_pass2<<<256,  256, 0, stream>>>(Abar, Bbar, Mv0);
    k_pass3<<<BB * CC * 2, 64, 0, stream>>>(w_, mask, e_, a_, Bbar, readv);
    k_final<<<1024, 256, 0, stream>>>(readv, skill, k_emb, fW, fbias,
                                      pW, pbias, out);
}

// Round 11
// 208.754 us; speedup vs baseline: 1.8321x; 1.0353x over previous
//
#include <hip/hip_runtime.h>
#include <hip/hip_bf16.h>
#include <math.h>

// Problem constants (fixed by the reference)
#define BB 32      // batch
#define SS 2048    // seq len
#define DD 64      // dim_s
#define MM 32      // size_m
#define NSKILL 4096
#define CC 64      // scan chunks
#define LL 32      // chunk length = SS/CC
#define NOUT (BB * (SS - 1))   // 65504

__device__ __forceinline__ float sigmoidf_(float x) {
    return 1.f / (1.f + __expf(-x));
}
__device__ __forceinline__ float tanhf_(float x) {
    float t = __expf(-2.f * fabsf(x));
    float r = (1.f - t) / (1.f + t);
    return copysignf(r, x);
}

// ---------------------------------------------------------------------------
// Kernel 1 (k_front): per 64-token block (= 2 scan chunks):
//   phase W : w = softmax(k@Mk^T)     (Mk rows in VGPRs, k broadcast from LDS)
//   phase EA: e = sig(v@eW), a = tanh(v@aW)  (weight cols in VGPRs, v broadcast)
//   phase C : compose chunk operators (Abar,Bbar) in-block (was k_pass1)
// Eliminates pass1's 40MB re-read of w/e/a + one launch.
// LDS: stage 16K + w 8K + e/a 32K + mask .25K = 56.25K -> 2 blocks/CU.
// ---------------------------------------------------------------------------
__global__ __launch_bounds__(256, 2) void k_front(
    const int* __restrict__ skill, const int* __restrict__ resp,
    const float* __restrict__ k_emb, const float* __restrict__ v_emb,
    const float* __restrict__ Mk,
    const float* __restrict__ eW, const float* __restrict__ eb,
    const float* __restrict__ aW, const float* __restrict__ ab,
    const float* __restrict__ mask,
    float* __restrict__ w_out, float* __restrict__ e_out, float* __restrict__ a_out,
    float* __restrict__ Abar, float* __restrict__ Bbar)
{
    __shared__ float stage[64 * 64];     // k rows, then v rows
    __shared__ float w_lds[64 * 32];
    __shared__ float ea_lds[2 * 64 * 64]; // e | a ; later aliased as exchange buf
    __shared__ float mk_lds[64];
    const int tid = threadIdx.x;
    const int g = blockIdx.x;            // 64-token group
    const int l = tid & 63;
    const int wv = tid >> 6;

    if (tid < 64) mk_lds[tid] = mask[g * 64 + tid];

    // ---- stage k rows (64 x 64) ----
    #pragma unroll
    for (int p = 0; p < 4; ++p) {
        const int r = p * 16 + (tid >> 4);
        const int t = g * 64 + r;
        const float4 kv = ((const float4*)(k_emb + (size_t)skill[t] * DD))[tid & 15];
        *(float4*)&stage[r * 64 + (tid & 15) * 4] = kv;
    }
    __syncthreads();

    // ---- W phase: lane = (m, token-half), 16 tokens per wave ----
    {
        const int m  = l & 31;
        const int th = l >> 5;
        float4 mk4[16];
        const float4* mkp = (const float4*)(Mk + m * DD);
        #pragma unroll
        for (int q = 0; q < 16; ++q) mk4[q] = mkp[q];

        for (int j = 0; j < 8; ++j) {
            const int tl = wv * 16 + j * 2 + th;
            const float4* kp = (const float4*)&stage[tl * 64];
            float a0 = 0.f, a1 = 0.f, a2 = 0.f, a3 = 0.f;
            #pragma unroll
            for (int q = 0; q < 16; ++q) {
                const float4 kv = kp[q];                 // uniform broadcast
                a0 = fmaf(kv.x, mk4[q].x, a0);
                a1 = fmaf(kv.y, mk4[q].y, a1);
                a2 = fmaf(kv.z, mk4[q].z, a2);
                a3 = fmaf(kv.w, mk4[q].w, a3);
            }
            const float lg = (a0 + a1) + (a2 + a3);
            float mx = lg;
            #pragma unroll
            for (int off = 16; off >= 1; off >>= 1) mx = fmaxf(mx, __shfl_xor(mx, off));
            const float ev = __expf(lg - mx);
            float sm = ev;
            #pragma unroll
            for (int off = 16; off >= 1; off >>= 1) sm += __shfl_xor(sm, off);
            w_lds[tl * 32 + m] = ev / sm;
        }
    }
    __syncthreads();   // w_lds complete; all waves done reading k-stage

    // coalesced global store of w (2048 floats)
    #pragma unroll
    for (int i = 0; i < 8; ++i) {
        const int idx = i * 256 + tid;
        w_out[(size_t)g * 2048 + idx] = w_lds[idx];
    }

    // ---- stage v rows (overwrite k-stage) ----
    #pragma unroll
    for (int p = 0; p < 4; ++p) {
        const int r = p * 16 + (tid >> 4);
        const int t = g * 64 + r;
        const int xc = skill[t] + NSKILL * resp[t];
        const float4 vv = ((const float4*)(v_emb + (size_t)xc * DD))[tid & 15];
        *(float4*)&stage[r * 64 + (tid & 15) * 4] = vv;
    }
    __syncthreads();

    // ---- EA phase: lane = output d; weight columns in VGPRs ----
    {
        float ew[64], aw[64];
        #pragma unroll
        for (int i = 0; i < 64; ++i) ew[i] = eW[i * DD + l];   // coalesced
        #pragma unroll
        for (int i = 0; i < 64; ++i) aw[i] = aW[i * DD + l];
        const float ebd = eb[l], abd = ab[l];

        for (int j = 0; j < 16; ++j) {
            const int tl = wv * 16 + j;
            const float4* vp = (const float4*)&stage[tl * 64];
            float e0 = ebd, e1 = 0.f, e2 = 0.f, e3 = 0.f;
            float x0 = abd, x1 = 0.f, x2 = 0.f, x3 = 0.f;
            #pragma unroll
            for (int q = 0; q < 16; ++q) {
                const float4 vv = vp[q];                 // uniform broadcast
                e0 = fmaf(vv.x, ew[4*q+0], e0);
                e1 = fmaf(vv.y, ew[4*q+1], e1);
                e2 = fmaf(vv.z, ew[4*q+2], e2);
                e3 = fmaf(vv.w, ew[4*q+3], e3);
                x0 = fmaf(vv.x, aw[4*q+0], x0);
                x1 = fmaf(vv.y, aw[4*q+1], x1);
                x2 = fmaf(vv.z, aw[4*q+2], x2);
                x3 = fmaf(vv.w, aw[4*q+3], x3);
            }
            const float es = sigmoidf_((e0 + e1) + (e2 + e3));
            const float as = tanhf_((x0 + x1) + (x2 + x3));
            const size_t t = (size_t)(g * 64 + tl);
            e_out[t * DD + l] = es;                      // 256B contiguous
            a_out[t * DD + l] = as;
            ea_lds[tl * 64 + l] = es;
            ea_lds[4096 + tl * 64 + l] = as;
        }
    }
    __syncthreads();   // e/a in LDS complete

    // ---- Compose phase (was k_pass1): 2 chunks x 2 half-waves ----
    const int ch = wv >> 1;      // chunk 0/1 within block
    const int hf = wv & 1;       // half: steps [0,16) or [16,32)
    float Ab[32], Bb[32];
    #pragma unroll
    for (int i = 0; i < 32; ++i) { Ab[i] = 1.f; Bb[i] = 0.f; }

    for (int j = 0; j < 16; ++j) {
        const int t = ch * 32 + hf * 16 + j;
        const float ed = ea_lds[t * 64 + l];             // lane-consecutive
        const float ad = ea_lds[4096 + t * 64 + l];
        const float msk = (mk_lds[t] == 1.f) ? 1.f : 0.f;
        const float4* wr = (const float4*)&w_lds[t * 32];
        #pragma unroll
        for (int u = 0; u < 8; ++u) {
            float4 wq = wr[u];                           // uniform broadcast
            wq.x *= msk; wq.y *= msk; wq.z *= msk; wq.w *= msk;
            float t1;
            t1 = fmaf(-wq.x, ed, 1.f); Ab[4*u+0] *= t1; Bb[4*u+0] = fmaf(Bb[4*u+0], t1, wq.x * ad);
            t1 = fmaf(-wq.y, ed, 1.f); Ab[4*u+1] *= t1; Bb[4*u+1] = fmaf(Bb[4*u+1], t1, wq.y * ad);
            t1 = fmaf(-wq.z, ed, 1.f); Ab[4*u+2] *= t1; Bb[4*u+2] = fmaf(Bb[4*u+2], t1, wq.z * ad);
            t1 = fmaf(-wq.w, ed, 1.f); Ab[4*u+3] *= t1; Bb[4*u+3] = fmaf(Bb[4*u+3], t1, wq.w * ad);
        }
    }
    __syncthreads();   // everyone done reading ea_lds/w_lds -> safe to alias

    float* xch = ea_lds;   // [chunk][A|B][32 m][64 d] = 8192 floats (32KB)
    if (hf == 0) {         // first half publishes (Aa, Ba)
        #pragma unroll
        for (int i = 0; i < 32; ++i) {
            xch[((ch * 2 + 0) * 32 + i) * 64 + l] = Ab[i];
            xch[((ch * 2 + 1) * 32 + i) * 64 + l] = Bb[i];
        }
    }
    __syncthreads();
    if (hf == 1) {         // second half combines: A=Aa*Ab, B=Ba*Ab+Bb
        const size_t base = ((size_t)g * 2 + ch) * (MM * DD);
        #pragma unroll
        for (int i = 0; i < 32; ++i) {
            const float Aa = xch[((ch * 2 + 0) * 32 + i) * 64 + l];
            const float Ba = xch[((ch * 2 + 1) * 32 + i) * 64 + l];
            Abar[base + i * 64 + l] = Aa * Ab[i];                  // coalesced
            Bbar[base + i * 64 + l] = fmaf(Ba, Ab[i], Bb[i]);
        }
    }
}

// ---------------------------------------------------------------------------
// Kernel 2 (scan pass 2): sequential over 64 chunks, parallel over B*M*D.
// Unroll x4: batch 8 independent loads per 4 dependent FMAs (64 -> 16
// latency round-trips). Writes chunk-start states IN PLACE into Bbar.
// ---------------------------------------------------------------------------
__global__ __launch_bounds__(256, 2) void k_pass2(
    const float* __restrict__ Abar, float* __restrict__ Bbar_cst,
    const float* __restrict__ Mv0)
{
    const int idx = blockIdx.x * 256 + threadIdx.x;   // over B*M*D = 65536
    const int b = idx >> 11;
    const int md = idx & 2047;
    float s = Mv0[md];
    for (int c = 0; c < CC; c += 4) {
        const int o0 = ((b * CC + c) << 11) + md;
        const float sa0 = Abar[o0];
        const float sb0 = Bbar_cst[o0];
        const float sa1 = Abar[o0 + 2048];
        const float sb1 = Bbar_cst[o0 + 2048];
        const float sa2 = Abar[o0 + 4096];
        const float sb2 = Bbar_cst[o0 + 4096];
        const float sa3 = Abar[o0 + 6144];
        const float sb3 = Bbar_cst[o0 + 6144];
        Bbar_cst[o0]        = s; s = fmaf(s, sa0, sb0);
        Bbar_cst[o0 + 2048] = s; s = fmaf(s, sa1, sb1);
        Bbar_cst[o0 + 4096] = s; s = fmaf(s, sa2, sb2);
        Bbar_cst[o0 + 6144] = s; s = fmaf(s, sa3, sb3);
    }
}

// ---------------------------------------------------------------------------
// Kernel 3 (scan pass 3, d-split): 2 blocks per (b,chunk). lane=(m-half, d-off);
// Mv[16]/lane; read partials folded across m-halves with shfl_xor(32).
// ---------------------------------------------------------------------------
__global__ __launch_bounds__(64, 4) void k_pass3(
    const float* __restrict__ w, const float* __restrict__ mask,
    const float* __restrict__ e, const float* __restrict__ a,
    const float* __restrict__ cstate, float* __restrict__ readv)
{
    __shared__ float4 wl[LL * MM / 4];   // masked w  (full 32 m)
    __shared__ float4 wn[LL * MM / 4];   // unmasked w, t+1
    const int lane = threadIdx.x;
    const int bc = blockIdx.x >> 1;
    const int dh = blockIdx.x & 1;
    const int b = bc / CC;
    const int c = bc % CC;
    const int t0 = c * LL;
    const bool last = (c == CC - 1);
    const int dof = lane & 31;
    const int mh  = lane >> 5;

    const float4* wg  = (const float4*)(w + (size_t)(b * SS + t0) * MM);
    const float4* wg2 = (const float4*)(w + (size_t)(b * SS + t0 + 1) * MM);
    #pragma unroll
    for (int u = 0; u < 4; ++u) {
        const int q4 = u * 64 + lane;
        const int j = q4 >> 3;
        const float s = (mask[b * SS + t0 + j] == 1.f) ? 1.f : 0.f;
        float4 wq = wg[q4];
        wq.x *= s; wq.y *= s; wq.z *= s; wq.w *= s;
        wl[q4] = wq;
        float4 wq2;
        if (last && q4 >= 248) wq2 = make_float4(0.f, 0.f, 0.f, 0.f);
        else                   wq2 = wg2[q4];
        wn[q4] = wq2;
    }
    __syncthreads();

    float Mv[16];
    const float* cs = cstate + (size_t)bc * MM * DD + (size_t)(mh * 16) * DD
                      + dh * 32 + dof;
    #pragma unroll
    for (int i = 0; i < 16; ++i) Mv[i] = cs[i * DD];

    const float* ep = e + (size_t)(b * SS + t0) * DD + dh * 32 + dof;
    const float* ap = a + (size_t)(b * SS + t0) * DD + dh * 32 + dof;
    float* ro = readv + (size_t)(b * SS + t0 + 1) * DD + dh * 32 + dof;
    for (int j = 0; j < LL; ++j) {
        const float ed = ep[j * DD];
        const float ad = ap[j * DD];
        const float4* wlj = wl + j * 8 + mh * 4;
        const float4* wnj = wn + j * 8 + mh * 4;
        float r0 = 0.f, r1 = 0.f, r2 = 0.f, r3 = 0.f;
        #pragma unroll
        for (int u = 0; u < 4; ++u) {
            const float4 wq = wlj[u];
            const float4 w2 = wnj[u];
            float t1;
            t1 = fmaf(-wq.x, ed, 1.f); Mv[4*u+0] = fmaf(Mv[4*u+0], t1, wq.x * ad); r0 = fmaf(w2.x, Mv[4*u+0], r0);
            t1 = fmaf(-wq.y, ed, 1.f); Mv[4*u+1] = fmaf(Mv[4*u+1], t1, wq.y * ad); r1 = fmaf(w2.y, Mv[4*u+1], r1);
            t1 = fmaf(-wq.z, ed, 1.f); Mv[4*u+2] = fmaf(Mv[4*u+2], t1, wq.z * ad); r2 = fmaf(w2.z, Mv[4*u+2], r2);
            t1 = fmaf(-wq.w, ed, 1.f); Mv[4*u+3] = fmaf(Mv[4*u+3], t1, wq.w * ad); r3 = fmaf(w2.w, Mv[4*u+3], r3);
        }
        float r = (r0 + r1) + (r2 + r3);
        r += __shfl_xor(r, 32);              // fold the two m-halves
        if (mh == 0 && !(last && j == LL - 1))
            ro[j * DD] = r;
    }
}

// ---------------------------------------------------------------------------
// Kernel 4: p = tanh([read,k]@fW+fb)@pW + pb. 1024 blocks x 256 thr,
// 64 outputs/block. lane = f-column d; fW column in 128 VGPRs; read/k rows
// staged in LDS (broadcast reads); p via full-wave shfl reduce.
// ---------------------------------------------------------------------------
__global__ __launch_bounds__(256, 2) void k_final(
    const float* __restrict__ readv, const int* __restrict__ skill,
    const float* __restrict__ k_emb,
    const float* __restrict__ fW, const float* __restrict__ fb,
    const float* __restrict__ pW, const float* __restrict__ pb,
    float* __restrict__ out)
{
    __shared__ float rst[64][64];
    __shared__ float kst[64][64];
    __shared__ float pbuf[64];
    const int tid = threadIdx.x;
    const int g = blockIdx.x;
    #pragma unroll
    for (int p = 0; p < 4; ++p) {
        const int r = p * 16 + (tid >> 4);
        int o = g * 64 + r;
        if (o >= NOUT) o = 0;                       // clamp (last block only)
        const int b = o / (SS - 1);
        const int s = o - b * (SS - 1) + 1;         // 1..2047
        const size_t tok = (size_t)b * SS + s;
        const int q = tid & 15;
        *(float4*)&rst[r][q * 4] = ((const float4*)(readv + tok * DD))[q];
        *(float4*)&kst[r][q * 4] = ((const float4*)(k_emb + (size_t)skill[tok] * DD))[q];
    }
    const int l = tid & 63;
    const int w = tid >> 6;
    float fw[128];
    #pragma unroll
    for (int i = 0; i < 128; ++i) fw[i] = fW[i * DD + l];   // coalesced
    const float fbd = fb[l], pwd = pW[l];
    __syncthreads();

    for (int j = 0; j < 16; ++j) {
        const int tl = w * 16 + j;
        const float4* rp = (const float4*)&rst[tl][0];
        const float4* kp = (const float4*)&kst[tl][0];
        float f0 = fbd, f1 = 0.f, f2 = 0.f, f3 = 0.f;
        #pragma unroll
        for (int q = 0; q < 16; ++q) {
            const float4 rv = rp[q];
            f0 = fmaf(rv.x, fw[4*q+0], f0);
            f1 = fmaf(rv.y, fw[4*q+1], f1);
            f2 = fmaf(rv.z, fw[4*q+2], f2);
            f3 = fmaf(rv.w, fw[4*q+3], f3);
        }
        #pragma unroll
        for (int q = 0; q < 16; ++q) {
            const float4 kv = kp[q];
            f0 = fmaf(kv.x, fw[64+4*q+0], f0);
            f1 = fmaf(kv.y, fw[64+4*q+1], f1);
            f2 = fmaf(kv.z, fw[64+4*q+2], f2);
            f3 = fmaf(kv.w, fw[64+4*q+3], f3);
        }
        float pv = tanhf_((f0 + f1) + (f2 + f3)) * pwd;
        #pragma unroll
        for (int off = 32; off >= 1; off >>= 1) pv += __shfl_xor(pv, off);
        if (l == 0) pbuf[tl] = pv;
    }
    __syncthreads();
    if (tid < 64) {
        const int o = g * 64 + tid;
        if (o < NOUT) out[o] = pbuf[tid] + pb[0];
    }
}

// ---------------------------------------------------------------------------
extern "C" void kernel_launch(void* const* d_in, const int* in_sizes, int n_in,
                              void* d_out, int out_size, void* d_ws, size_t ws_size,
                              hipStream_t stream)
{
    const int*   response = (const int*)d_in[1];
    const int*   skill    = (const int*)d_in[2];
    const float* mask     = (const float*)d_in[3];
    const float* k_emb    = (const float*)d_in[4];
    const float* v_emb    = (const float*)d_in[5];
    const float* Mk       = (const float*)d_in[6];
    const float* Mv0      = (const float*)d_in[7];
    const float* eW       = (const float*)d_in[8];
    const float* ebias    = (const float*)d_in[9];
    const float* aW       = (const float*)d_in[10];
    const float* abias    = (const float*)d_in[11];
    const float* fW       = (const float*)d_in[12];
    const float* fbias    = (const float*)d_in[13];
    const float* pW       = (const float*)d_in[14];
    const float* pbias    = (const float*)d_in[15];
    float* out = (float*)d_out;

    // workspace layout (floats); total 23,068,672 floats = 88.0 MiB
    float* ws    = (float*)d_ws;
    float* w_    = ws;                               // B*S*M   = 2,097,152
    float* e_    = w_    + (size_t)BB * SS * MM;     // B*S*D   = 4,194,304
    float* a_    = e_    + (size_t)BB * SS * DD;
    float* Abar  = a_    + (size_t)BB * SS * DD;     // B*C*M*D = 4,194,304
    float* Bbar  = Abar  + (size_t)BB * CC * MM * DD; // doubles as cstate
    float* readv = Bbar  + (size_t)BB * CC * MM * DD; // B*S*D (row s=0 unused)

    k_front<<<1024, 256, 0, stream>>>(skill, response, k_emb, v_emb, Mk,
                                      eW, ebias, aW, abias, mask,
                                      w_, e_, a_, Abar, Bbar);
    k_pass2<<<256,  256, 0, stream>>>(Abar, Bbar, Mv0);
    k_pass3<<<BB * CC * 2, 64, 0, stream>>>(w_, mask, e_, a_, Bbar, readv);
    k_final<<<1024, 256, 0, stream>>>(readv, skill, k_emb, fW, fbias,
                                      pW, pbias, out);
}